// Round 7
// baseline (336.481 us; speedup 1.0000x reference)
//
#include <hip/hip_runtime.h>
#include <hip/hip_bf16.h>

#define NN 500000
#define NBLK_CM 1009   // colmax blocks: 1009 * 496 rows >= NN
// feats = [mu_in(128) | mu_not(128) | enc(128)]; H1=256, H2=128, H3=64

typedef unsigned short ushort_t;
typedef __attribute__((ext_vector_type(8))) __bf16 bf16x8;
typedef __attribute__((ext_vector_type(2))) __bf16 bf16x2;
typedef __attribute__((ext_vector_type(4))) float f32x4;
typedef __attribute__((ext_vector_type(4))) unsigned uint4v;

__device__ inline ushort_t f2bf(float f) {
  unsigned u = __builtin_bit_cast(unsigned, f);
  return (ushort_t)((u + 0x7FFFu + ((u >> 16) & 1u)) >> 16);
}
__device__ inline float lrelu(float v) { return fmaxf(v, 0.f) + 0.01f * fminf(v, 0.f); }
__device__ inline unsigned pk2(float lo, float hi) {
  bf16x2 v; v[0] = (__bf16)lo; v[1] = (__bf16)hi;
  return __builtin_bit_cast(unsigned, v);
}
__device__ inline bf16x8 mk8(unsigned w0, unsigned w1, unsigned w2, unsigned w3) {
  uint4v u; u.x = w0; u.y = w1; u.z = w2; u.w = w3;
  return __builtin_bit_cast(bf16x8, u);
}
#define SHF(v, s) ((unsigned)__shfl((int)(v), (s), 64))
#define SBAR() __builtin_amdgcn_sched_barrier(0)

// ---------------- K_colmax: masked per-column max -> per-block partials (NO atomics) ----
// Round-6 diagnosis: 500K device-scope atomicMax ops onto 256 contiguous dwords were a
// ~220 us fixed serialization (duration invariant to FETCH_SIZE). Now each block writes
// its 256 partial maxima plain; k_redmax folds them.
__global__ __launch_bounds__(256) void k_colmax(
    const float* __restrict__ enc, const int* __restrict__ cs,
    float* __restrict__ partials)            // [NBLK_CM][256]: in(128)|not(128)
{
  __shared__ float4 s_in[256], s_not[256];
  const int tid = threadIdx.x;
  const int c4 = tid & 31;    // float4-column 0..31
  const int rs = tid >> 5;    // row slice 0..7
  const long base = (long)blockIdx.x * 496;
  float4 mi = {0.f, 0.f, 0.f, 0.f}, mn = {0.f, 0.f, 0.f, 0.f};
  const float4* e4 = (const float4*)enc;
  #pragma unroll 4
  for (int it = 0; it < 62; ++it) {
    long r = base + rs + 8L * it;
    if (r < NN) {
      float4 v = e4[r * 32 + c4];
      bool ins = cs[r] > 0;
      mi.x = fmaxf(mi.x, ins ? v.x : 0.f); mi.y = fmaxf(mi.y, ins ? v.y : 0.f);
      mi.z = fmaxf(mi.z, ins ? v.z : 0.f); mi.w = fmaxf(mi.w, ins ? v.w : 0.f);
      mn.x = fmaxf(mn.x, ins ? 0.f : v.x); mn.y = fmaxf(mn.y, ins ? 0.f : v.y);
      mn.z = fmaxf(mn.z, ins ? 0.f : v.z); mn.w = fmaxf(mn.w, ins ? 0.f : v.w);
    }
  }
  s_in[tid] = mi; s_not[tid] = mn;
  __syncthreads();
  if (tid < 32) {              // tid<32 holds slice rs=0, col c4=tid in registers
    for (int j = 1; j < 8; ++j) {
      float4 a = s_in[j * 32 + tid], b = s_not[j * 32 + tid];
      mi.x = fmaxf(mi.x, a.x); mi.y = fmaxf(mi.y, a.y);
      mi.z = fmaxf(mi.z, a.z); mi.w = fmaxf(mi.w, a.w);
      mn.x = fmaxf(mn.x, b.x); mn.y = fmaxf(mn.y, b.y);
      mn.z = fmaxf(mn.z, b.z); mn.w = fmaxf(mn.w, b.w);
    }
    float* po = partials + (size_t)blockIdx.x * 256;
    ((float4*)po)[tid] = mi;           // cols 4t..4t+3 of mu_in partial
    ((float4*)(po + 128))[tid] = mn;   // mu_not partial
  }
}

// ---------------- K_redmax: fold per-block partials -> mu_in/mu_not (plain fmax) -------
__global__ __launch_bounds__(256) void k_redmax(
    const float* __restrict__ partials,
    float* __restrict__ mu_in, float* __restrict__ mu_not)
{
  const int tid = threadIdx.x;
  float m = 0.f;               // identity: masked max >= 0 (all-0 rows participate)
  #pragma unroll 8
  for (int b = 0; b < NBLK_CM; ++b)
    m = fmaxf(m, partials[(size_t)b * 256 + tid]);
  if (tid < 128) mu_in[tid] = m;
  else           mu_not[tid - 128] = m;
}

// ---------------- K_mlp: persistent, weights LDS-resident, barrier-free loop -------------
// (byte-identical to round 6 -- verified: ~80 us, no spill, absmax bit-stable)
__global__ __launch_bounds__(512)
__attribute__((amdgpu_waves_per_eu(2, 2)))
void k_mlp(
    const float* __restrict__ enc,
    const float* __restrict__ W1, const float* __restrict__ b1,
    const float* __restrict__ W2, const float* __restrict__ b2,
    const float* __restrict__ W3, const float* __restrict__ b3,
    const float* __restrict__ W4, const float* __restrict__ b4,
    const float* __restrict__ mu_in, const float* __restrict__ mu_not,
    float* __restrict__ eL, float* __restrict__ psum)
{
  __shared__ ushort_t sW1[256 * 136];   // [n1][k=e]   69632 B
  __shared__ ushort_t sW2[128 * 264];   // [n2][k=n1]  67584 B
  __shared__ ushort_t sW3[64 * 136];    // [n3][k=n2]  17408 B
  __shared__ float sC[520];             // c[256]|b2[128]|b3[64]|W4[64]|b4
  __shared__ float sT[512];             // cvec partials

  const int tid = threadIdx.x;

  // ---- one-time staging: fp32 global -> bf16 LDS (transposed; coalesced in n) ----
  for (int idx = tid; idx < 32768; idx += 512) {
    int n = idx & 255, k = idx >> 8;              // n1, e
    sW1[n * 136 + k] = f2bf(W1[(256 + k) * 256 + n]);
  }
  for (int idx = tid; idx < 32768; idx += 512) {
    int n = idx & 127, k = idx >> 7;              // n2, n1
    sW2[n * 264 + k] = f2bf(W2[k * 128 + n]);
  }
  for (int idx = tid; idx < 8192; idx += 512) {
    int n = idx & 63, k = idx >> 6;               // n3, n2
    sW3[n * 136 + k] = f2bf(W3[k * 64 + n]);
  }
  if (tid >= 256 && tid < 384) sC[tid] = b2[tid - 256];
  else if (tid >= 384 && tid < 448) sC[tid] = b3[tid - 384];
  else if (tid >= 448) sC[tid] = W4[tid - 448];
  if (tid == 0) sC[512] = b4[0];
  { // inlined cvec: c[j] = b1[j] + mu_in . W1[0:128,j] + mu_not . W1[128:256,j]
    const int j = tid & 255, h = tid >> 8;        // h = 0..1
    float c = h ? 0.f : b1[j];
    #pragma unroll 8
    for (int e = 64 * h; e < 64 * h + 64; ++e) {
      c += mu_in[e]  * W1[e * 256 + j];
      c += mu_not[e] * W1[(128 + e) * 256 + j];
    }
    sT[tid] = c;
  }
  __syncthreads();
  if (tid < 256) sC[tid] = sT[tid] + sT[tid + 256];
  __syncthreads();   // last block-wide barrier

  const int wave = tid >> 6, lane = tid & 63;
  const int lr = lane & 15, lg = lane >> 4;
  const int wid = blockIdx.x * 8 + wave;          // 0..2047
  const int selhi = lane & 32;
  const int srcLo = lr + ((lane & 16) << 1);      // butterfly partner lanes
  const int srcHi = srcLo + 16;

  const ushort_t* w1p = sW1 + lr * 136 + 8 * lg;  // + mt*2176 + kt*32
  const ushort_t* w2p = sW2 + lr * 264 + 8 * lg;  // + mt*4224 + kt*32
  const ushort_t* w3p = sW3 + lr * 136 + 8 * lg;

  float es = 0.f;
  bf16x8 B1[4];

  // preload + convert first 16-row group (row = wid*16 + lr, always < NN)
  {
    const float4* p = (const float4*)(enc + (size_t)(wid * 16 + lr) * 128);
    #pragma unroll
    for (int kt = 0; kt < 4; ++kt) {
      float4 f0 = p[kt * 8 + lg * 2], f1 = p[kt * 8 + lg * 2 + 1];
      bf16x8 a;
      a[0] = (__bf16)f0.x; a[1] = (__bf16)f0.y; a[2] = (__bf16)f0.z; a[3] = (__bf16)f0.w;
      a[4] = (__bf16)f1.x; a[5] = (__bf16)f1.y; a[6] = (__bf16)f1.z; a[7] = (__bf16)f1.w;
      B1[kt] = a;
    }
  }

  for (int r0 = wid * 16; r0 < NN; r0 += 32768) {
    // ---- L1: mt-pairs with immediate epilogue+butterfly -> B2[p] ----
    bf16x8 B2[8];
    #pragma unroll
    for (int p = 0; p < 8; ++p) {
      f32x4 a0 = (f32x4){0.f, 0.f, 0.f, 0.f}, a1 = (f32x4){0.f, 0.f, 0.f, 0.f};
      #pragma unroll
      for (int kt = 0; kt < 4; ++kt) {
        bf16x8 wA = *(const bf16x8*)(w1p + (2 * p) * 2176 + kt * 32);
        bf16x8 wB = *(const bf16x8*)(w1p + (2 * p + 1) * 2176 + kt * 32);
        a0 = __builtin_amdgcn_mfma_f32_16x16x32_bf16(wA, B1[kt], a0, 0, 0, 0);
        a1 = __builtin_amdgcn_mfma_f32_16x16x32_bf16(wB, B1[kt], a1, 0, 0, 0);
      }
      float4 cb0 = *(const float4*)(sC + 16 * (2 * p) + 4 * lg);
      float4 cb1 = *(const float4*)(sC + 16 * (2 * p + 1) + 4 * lg);
      unsigned q0 = pk2(lrelu(a0[0] + cb0.x), lrelu(a0[1] + cb0.y));
      unsigned q1 = pk2(lrelu(a0[2] + cb0.z), lrelu(a0[3] + cb0.w));
      unsigned q2 = pk2(lrelu(a1[0] + cb1.x), lrelu(a1[1] + cb1.y));
      unsigned q3 = pk2(lrelu(a1[2] + cb1.z), lrelu(a1[3] + cb1.w));
      unsigned w0a = SHF(q0, srcLo), w0b = SHF(q2, srcLo);
      unsigned w1a = SHF(q1, srcLo), w1b = SHF(q3, srcLo);
      unsigned w2a = SHF(q0, srcHi), w2b = SHF(q2, srcHi);
      unsigned w3a = SHF(q1, srcHi), w3b = SHF(q3, srcHi);
      B2[p] = mk8(selhi ? w0b : w0a, selhi ? w1b : w1a,
                  selhi ? w2b : w2a, selhi ? w3b : w3a);
    }
    SBAR();   // phase fence: keep L2's ds_reads from hoisting into L1
    // ---- L2: mt-pairs -> B3[p] ----
    bf16x8 B3[4];
    #pragma unroll
    for (int p = 0; p < 4; ++p) {
      f32x4 a0 = (f32x4){0.f, 0.f, 0.f, 0.f}, a1 = (f32x4){0.f, 0.f, 0.f, 0.f};
      #pragma unroll
      for (int kt = 0; kt < 8; ++kt) {
        bf16x8 wA = *(const bf16x8*)(w2p + (2 * p) * 4224 + kt * 32);
        bf16x8 wB = *(const bf16x8*)(w2p + (2 * p + 1) * 4224 + kt * 32);
        a0 = __builtin_amdgcn_mfma_f32_16x16x32_bf16(wA, B2[kt], a0, 0, 0, 0);
        a1 = __builtin_amdgcn_mfma_f32_16x16x32_bf16(wB, B2[kt], a1, 0, 0, 0);
      }
      float4 cb0 = *(const float4*)(sC + 256 + 16 * (2 * p) + 4 * lg);
      float4 cb1 = *(const float4*)(sC + 256 + 16 * (2 * p + 1) + 4 * lg);
      unsigned q0 = pk2(lrelu(a0[0] + cb0.x), lrelu(a0[1] + cb0.y));
      unsigned q1 = pk2(lrelu(a0[2] + cb0.z), lrelu(a0[3] + cb0.w));
      unsigned q2 = pk2(lrelu(a1[0] + cb1.x), lrelu(a1[1] + cb1.y));
      unsigned q3 = pk2(lrelu(a1[2] + cb1.z), lrelu(a1[3] + cb1.w));
      unsigned w0a = SHF(q0, srcLo), w0b = SHF(q2, srcLo);
      unsigned w1a = SHF(q1, srcLo), w1b = SHF(q3, srcLo);
      unsigned w2a = SHF(q0, srcHi), w2b = SHF(q2, srcHi);
      unsigned w3a = SHF(q1, srcHi), w3b = SHF(q3, srcHi);
      B3[p] = mk8(selhi ? w0b : w0a, selhi ? w1b : w1a,
                  selhi ? w2b : w2a, selhi ? w3b : w3a);
    }
    SBAR();   // phase fence
    // ---- prefetch next 16-row group: issue here, consume at loop bottom.
    //      tA is live only across L3/L4 (the thin phase), not across L2.
    int rn = r0 + 32768; if (rn >= NN) rn = r0;   // last iter: dummy reload
    float4 tA[8];
    {
      const float4* p = (const float4*)(enc + (size_t)(rn + lr) * 128);
      #pragma unroll
      for (int kt = 0; kt < 4; ++kt) {
        tA[2 * kt]     = p[kt * 8 + lg * 2];
        tA[2 * kt + 1] = p[kt * 8 + lg * 2 + 1];
      }
    }
    SBAR();   // pin the load-issue position (do not sink into L3)
    // ---- L3 (mt-pairs) + L4 epilogue folded into W4 dot ----
    float dot = 0.f;
    #pragma unroll
    for (int p = 0; p < 2; ++p) {
      f32x4 a0 = (f32x4){0.f, 0.f, 0.f, 0.f}, a1 = (f32x4){0.f, 0.f, 0.f, 0.f};
      #pragma unroll
      for (int kt = 0; kt < 4; ++kt) {
        bf16x8 wA = *(const bf16x8*)(w3p + (2 * p) * 2176 + kt * 32);
        bf16x8 wB = *(const bf16x8*)(w3p + (2 * p + 1) * 2176 + kt * 32);
        a0 = __builtin_amdgcn_mfma_f32_16x16x32_bf16(wA, B3[kt], a0, 0, 0, 0);
        a1 = __builtin_amdgcn_mfma_f32_16x16x32_bf16(wB, B3[kt], a1, 0, 0, 0);
      }
      float4 cb0  = *(const float4*)(sC + 384 + 16 * (2 * p) + 4 * lg);
      float4 cb1  = *(const float4*)(sC + 384 + 16 * (2 * p + 1) + 4 * lg);
      float4 w4v0 = *(const float4*)(sC + 448 + 16 * (2 * p) + 4 * lg);
      float4 w4v1 = *(const float4*)(sC + 448 + 16 * (2 * p + 1) + 4 * lg);
      dot += lrelu(a0[0] + cb0.x) * w4v0.x + lrelu(a0[1] + cb0.y) * w4v0.y
           + lrelu(a0[2] + cb0.z) * w4v0.z + lrelu(a0[3] + cb0.w) * w4v0.w;
      dot += lrelu(a1[0] + cb1.x) * w4v1.x + lrelu(a1[1] + cb1.y) * w4v1.y
           + lrelu(a1[2] + cb1.z) * w4v1.z + lrelu(a1[3] + cb1.w) * w4v1.w;
    }
    dot += __shfl_xor(dot, 16, 64);
    dot += __shfl_xor(dot, 32, 64);
    float ev = expf(dot + sC[512]);
    if (lg == 0) eL[r0 + lr] = ev;
    es += ev;                        // 4x duplicated across lg, scaled at the end
    // ---- convert prefetched rows -> B1 for next iteration ----
    #pragma unroll
    for (int kt = 0; kt < 4; ++kt) {
      float4 f0 = tA[2 * kt], f1 = tA[2 * kt + 1];
      bf16x8 a;
      a[0] = (__bf16)f0.x; a[1] = (__bf16)f0.y; a[2] = (__bf16)f0.z; a[3] = (__bf16)f0.w;
      a[4] = (__bf16)f1.x; a[5] = (__bf16)f1.y; a[6] = (__bf16)f1.z; a[7] = (__bf16)f1.w;
      B1[kt] = a;
    }
  }
  // wave-wide partial softmax denominator (deterministic: one slot per wave)
  #pragma unroll
  for (int off = 1; off < 64; off <<= 1) es += __shfl_xor(es, off, 64);
  if (lane == 0) psum[wid] = 0.25f * es;
}

// ---------------- final reduce + normalize ----------------
__global__ __launch_bounds__(256) void k_finalsum(const float* __restrict__ psum,
                                                  float* __restrict__ scal)
{
  const int tid = threadIdx.x;
  float s = 0.f;
  #pragma unroll
  for (int k = 0; k < 8; ++k) s += psum[tid + k * 256];
  #pragma unroll
  for (int off = 1; off < 64; off <<= 1) s += __shfl_xor(s, off, 64);
  __shared__ float sr[4];
  if ((tid & 63) == 0) sr[tid >> 6] = s;
  __syncthreads();
  if (tid == 0) scal[0] = 1.f / (sr[0] + sr[1] + sr[2] + sr[3]);
}

__global__ __launch_bounds__(256) void k_norm(const float* __restrict__ eL,
                                              const float* __restrict__ scal,
                                              float* __restrict__ out)
{
  const float inv = scal[0];
  const int i = blockIdx.x * 256 + threadIdx.x;
  if (i < NN / 4) {
    float4 v = ((const float4*)eL)[i];
    float4 o = {v.x * inv, v.y * inv, v.z * inv, v.w * inv};
    ((float4*)out)[i] = o;
  }
}

extern "C" void kernel_launch(void* const* d_in, const int* in_sizes, int n_in,
                              void* d_out, int out_size, void* d_ws, size_t ws_size,
                              hipStream_t stream) {
  const float* enc = (const float*)d_in[0];
  const int*   cs  = (const int*)d_in[1];
  const float* W1  = (const float*)d_in[2];
  const float* b1  = (const float*)d_in[3];
  const float* W2  = (const float*)d_in[4];
  const float* b2  = (const float*)d_in[5];
  const float* W3  = (const float*)d_in[6];
  const float* b3  = (const float*)d_in[7];
  const float* W4  = (const float*)d_in[8];
  const float* b4  = (const float*)d_in[9];
  float* out = (float*)d_out;

  char* ws = (char*)d_ws;
  float* mu_in  = (float*)(ws + 0);        // 512 B
  float* mu_not = (float*)(ws + 512);      // 512 B
  float* psum   = (float*)(ws + 2048);     // 2048 floats = 8 KB
  float* scal   = (float*)(ws + 10240);    // 4 B
  float* eLbuf  = (float*)(ws + 12288);    // 2 MB (exp(logit) per row)
  // colmax partials alias the eL region: live only BEFORE k_mlp writes eL.
  float* partials = (float*)(ws + 12288);  // 1009*256*4 = 1,033,216 B <= 2 MB

  k_colmax<<<dim3(NBLK_CM), dim3(256), 0, stream>>>(enc, cs, partials);
  k_redmax<<<dim3(1), dim3(256), 0, stream>>>(partials, mu_in, mu_not);
  k_mlp<<<dim3(256), dim3(512), 0, stream>>>(enc, W1, b1, W2, b2, W3, b3, W4, b4,
                                             mu_in, mu_not, eLbuf, psum);
  k_finalsum<<<dim3(1), dim3(256), 0, stream>>>(psum, scal);
  k_norm<<<dim3(489), dim3(256), 0, stream>>>(eLbuf, scal, out);
}

// Round 8
// 192.660 us; speedup vs baseline: 1.7465x; 1.7465x over previous
//
#include <hip/hip_runtime.h>
#include <hip/hip_bf16.h>

#define NN 500000
#define NBLK_CM 2000   // colmax blocks: 2000 * 250 rows = 500,000 exact
// feats = [mu_in(128) | mu_not(128) | enc(128)]; H1=256, H2=128, H3=64

typedef unsigned short ushort_t;
typedef __attribute__((ext_vector_type(8))) __bf16 bf16x8;
typedef __attribute__((ext_vector_type(2))) __bf16 bf16x2;
typedef __attribute__((ext_vector_type(4))) float f32x4;
typedef __attribute__((ext_vector_type(4))) unsigned uint4v;

__device__ inline ushort_t f2bf(float f) {
  unsigned u = __builtin_bit_cast(unsigned, f);
  return (ushort_t)((u + 0x7FFFu + ((u >> 16) & 1u)) >> 16);
}
__device__ inline float lrelu(float v) { return fmaxf(v, 0.f) + 0.01f * fminf(v, 0.f); }
__device__ inline unsigned pk2(float lo, float hi) {
  bf16x2 v; v[0] = (__bf16)lo; v[1] = (__bf16)hi;
  return __builtin_bit_cast(unsigned, v);
}
__device__ inline bf16x8 mk8(unsigned w0, unsigned w1, unsigned w2, unsigned w3) {
  uint4v u; u.x = w0; u.y = w1; u.z = w2; u.w = w3;
  return __builtin_bit_cast(bf16x8, u);
}
#define SHF(v, s) ((unsigned)__shfl((int)(v), (s), 64))
#define SBAR() __builtin_amdgcn_sched_barrier(0)

// ---------------- K_colmax: masked per-column max -> per-block partials (NO atomics) ----
// 2000 blocks (8/CU resident -- 1009 underfilled the machine) x 250 rows exact.
__global__ __launch_bounds__(256) void k_colmax(
    const float* __restrict__ enc, const int* __restrict__ cs,
    float* __restrict__ partials)            // [NBLK_CM][256]: in(128)|not(128)
{
  __shared__ float4 s_in[256], s_not[256];
  const int tid = threadIdx.x;
  const int c4 = tid & 31;    // float4-column 0..31
  const int rs = tid >> 5;    // row slice 0..7
  const long base = (long)blockIdx.x * 250;
  float4 mi = {0.f, 0.f, 0.f, 0.f}, mn = {0.f, 0.f, 0.f, 0.f};
  const float4* e4 = (const float4*)enc;
  #pragma unroll 4
  for (int it = 0; it < 32; ++it) {        // 8 slices x 32 = 256 rows >= 250 (guarded)
    long r = base + rs + 8L * it;
    if (r < base + 250 && r < NN) {
      float4 v = e4[r * 32 + c4];
      bool ins = cs[r] > 0;
      mi.x = fmaxf(mi.x, ins ? v.x : 0.f); mi.y = fmaxf(mi.y, ins ? v.y : 0.f);
      mi.z = fmaxf(mi.z, ins ? v.z : 0.f); mi.w = fmaxf(mi.w, ins ? v.w : 0.f);
      mn.x = fmaxf(mn.x, ins ? 0.f : v.x); mn.y = fmaxf(mn.y, ins ? 0.f : v.y);
      mn.z = fmaxf(mn.z, ins ? 0.f : v.z); mn.w = fmaxf(mn.w, ins ? 0.f : v.w);
    }
  }
  s_in[tid] = mi; s_not[tid] = mn;
  __syncthreads();
  if (tid < 32) {              // tid<32 holds slice rs=0, col c4=tid in registers
    for (int j = 1; j < 8; ++j) {
      float4 a = s_in[j * 32 + tid], b = s_not[j * 32 + tid];
      mi.x = fmaxf(mi.x, a.x); mi.y = fmaxf(mi.y, a.y);
      mi.z = fmaxf(mi.z, a.z); mi.w = fmaxf(mi.w, a.w);
      mn.x = fmaxf(mn.x, b.x); mn.y = fmaxf(mn.y, b.y);
      mn.z = fmaxf(mn.z, b.z); mn.w = fmaxf(mn.w, b.w);
    }
    float* po = partials + (size_t)blockIdx.x * 256;
    ((float4*)po)[tid] = mi;           // cols 4t..4t+3 of mu_in partial
    ((float4*)(po + 128))[tid] = mn;   // mu_not partial
  }
}

// ---------------- K_red1: 64 blocks fold 2000 partial rows -> red2[64][256] ------------
// Round-7 diagnosis: single-block k_redmax (1009 stride-256 loads/thread) ran at
// ~390 cyc/load with no MLP -- 163 us. Spread the fold over 64 CUs.
__global__ __launch_bounds__(256) void k_red1(
    const float* __restrict__ partials, float* __restrict__ red2)
{
  const int tid = threadIdx.x, b = blockIdx.x;
  float m = 0.f;               // identity: masked max >= 0
  #pragma unroll 8
  for (int row = b; row < NBLK_CM; row += 64)
    m = fmaxf(m, partials[(size_t)row * 256 + tid]);
  red2[b * 256 + tid] = m;
}

// ---------------- K_red2: 1 block folds red2[64][256] -> mu_in/mu_not ------------------
__global__ __launch_bounds__(1024) void k_red2(
    const float* __restrict__ red2,
    float* __restrict__ mu_in, float* __restrict__ mu_not)
{
  __shared__ float sT[1024];
  const int tid = threadIdx.x;
  const int col = tid & 255, sl = tid >> 8;     // 4 slices x 16 rows
  float m = 0.f;
  #pragma unroll
  for (int j = 0; j < 16; ++j)
    m = fmaxf(m, red2[(sl * 16 + j) * 256 + col]);
  sT[tid] = m;
  __syncthreads();
  if (tid < 256) {
    m = fmaxf(fmaxf(sT[tid], sT[tid + 256]), fmaxf(sT[tid + 512], sT[tid + 768]));
    if (tid < 128) mu_in[tid] = m;
    else           mu_not[tid - 128] = m;
  }
}

// ---------------- K_mlp: persistent, weights LDS-resident, barrier-free loop -------------
// (byte-identical to round 6 -- verified: ~80 us, no spill, absmax bit-stable)
__global__ __launch_bounds__(512)
__attribute__((amdgpu_waves_per_eu(2, 2)))
void k_mlp(
    const float* __restrict__ enc,
    const float* __restrict__ W1, const float* __restrict__ b1,
    const float* __restrict__ W2, const float* __restrict__ b2,
    const float* __restrict__ W3, const float* __restrict__ b3,
    const float* __restrict__ W4, const float* __restrict__ b4,
    const float* __restrict__ mu_in, const float* __restrict__ mu_not,
    float* __restrict__ eL, float* __restrict__ psum)
{
  __shared__ ushort_t sW1[256 * 136];   // [n1][k=e]   69632 B
  __shared__ ushort_t sW2[128 * 264];   // [n2][k=n1]  67584 B
  __shared__ ushort_t sW3[64 * 136];    // [n3][k=n2]  17408 B
  __shared__ float sC[520];             // c[256]|b2[128]|b3[64]|W4[64]|b4
  __shared__ float sT[512];             // cvec partials

  const int tid = threadIdx.x;

  // ---- one-time staging: fp32 global -> bf16 LDS (transposed; coalesced in n) ----
  for (int idx = tid; idx < 32768; idx += 512) {
    int n = idx & 255, k = idx >> 8;              // n1, e
    sW1[n * 136 + k] = f2bf(W1[(256 + k) * 256 + n]);
  }
  for (int idx = tid; idx < 32768; idx += 512) {
    int n = idx & 127, k = idx >> 7;              // n2, n1
    sW2[n * 264 + k] = f2bf(W2[k * 128 + n]);
  }
  for (int idx = tid; idx < 8192; idx += 512) {
    int n = idx & 63, k = idx >> 6;               // n3, n2
    sW3[n * 136 + k] = f2bf(W3[k * 64 + n]);
  }
  if (tid >= 256 && tid < 384) sC[tid] = b2[tid - 256];
  else if (tid >= 384 && tid < 448) sC[tid] = b3[tid - 384];
  else if (tid >= 448) sC[tid] = W4[tid - 448];
  if (tid == 0) sC[512] = b4[0];
  { // inlined cvec: c[j] = b1[j] + mu_in . W1[0:128,j] + mu_not . W1[128:256,j]
    const int j = tid & 255, h = tid >> 8;        // h = 0..1
    float c = h ? 0.f : b1[j];
    #pragma unroll 8
    for (int e = 64 * h; e < 64 * h + 64; ++e) {
      c += mu_in[e]  * W1[e * 256 + j];
      c += mu_not[e] * W1[(128 + e) * 256 + j];
    }
    sT[tid] = c;
  }
  __syncthreads();
  if (tid < 256) sC[tid] = sT[tid] + sT[tid + 256];
  __syncthreads();   // last block-wide barrier

  const int wave = tid >> 6, lane = tid & 63;
  const int lr = lane & 15, lg = lane >> 4;
  const int wid = blockIdx.x * 8 + wave;          // 0..2047
  const int selhi = lane & 32;
  const int srcLo = lr + ((lane & 16) << 1);      // butterfly partner lanes
  const int srcHi = srcLo + 16;

  const ushort_t* w1p = sW1 + lr * 136 + 8 * lg;  // + mt*2176 + kt*32
  const ushort_t* w2p = sW2 + lr * 264 + 8 * lg;  // + mt*4224 + kt*32
  const ushort_t* w3p = sW3 + lr * 136 + 8 * lg;

  float es = 0.f;
  bf16x8 B1[4];

  // preload + convert first 16-row group (row = wid*16 + lr, always < NN)
  {
    const float4* p = (const float4*)(enc + (size_t)(wid * 16 + lr) * 128);
    #pragma unroll
    for (int kt = 0; kt < 4; ++kt) {
      float4 f0 = p[kt * 8 + lg * 2], f1 = p[kt * 8 + lg * 2 + 1];
      bf16x8 a;
      a[0] = (__bf16)f0.x; a[1] = (__bf16)f0.y; a[2] = (__bf16)f0.z; a[3] = (__bf16)f0.w;
      a[4] = (__bf16)f1.x; a[5] = (__bf16)f1.y; a[6] = (__bf16)f1.z; a[7] = (__bf16)f1.w;
      B1[kt] = a;
    }
  }

  for (int r0 = wid * 16; r0 < NN; r0 += 32768) {
    // ---- L1: mt-pairs with immediate epilogue+butterfly -> B2[p] ----
    bf16x8 B2[8];
    #pragma unroll
    for (int p = 0; p < 8; ++p) {
      f32x4 a0 = (f32x4){0.f, 0.f, 0.f, 0.f}, a1 = (f32x4){0.f, 0.f, 0.f, 0.f};
      #pragma unroll
      for (int kt = 0; kt < 4; ++kt) {
        bf16x8 wA = *(const bf16x8*)(w1p + (2 * p) * 2176 + kt * 32);
        bf16x8 wB = *(const bf16x8*)(w1p + (2 * p + 1) * 2176 + kt * 32);
        a0 = __builtin_amdgcn_mfma_f32_16x16x32_bf16(wA, B1[kt], a0, 0, 0, 0);
        a1 = __builtin_amdgcn_mfma_f32_16x16x32_bf16(wB, B1[kt], a1, 0, 0, 0);
      }
      float4 cb0 = *(const float4*)(sC + 16 * (2 * p) + 4 * lg);
      float4 cb1 = *(const float4*)(sC + 16 * (2 * p + 1) + 4 * lg);
      unsigned q0 = pk2(lrelu(a0[0] + cb0.x), lrelu(a0[1] + cb0.y));
      unsigned q1 = pk2(lrelu(a0[2] + cb0.z), lrelu(a0[3] + cb0.w));
      unsigned q2 = pk2(lrelu(a1[0] + cb1.x), lrelu(a1[1] + cb1.y));
      unsigned q3 = pk2(lrelu(a1[2] + cb1.z), lrelu(a1[3] + cb1.w));
      unsigned w0a = SHF(q0, srcLo), w0b = SHF(q2, srcLo);
      unsigned w1a = SHF(q1, srcLo), w1b = SHF(q3, srcLo);
      unsigned w2a = SHF(q0, srcHi), w2b = SHF(q2, srcHi);
      unsigned w3a = SHF(q1, srcHi), w3b = SHF(q3, srcHi);
      B2[p] = mk8(selhi ? w0b : w0a, selhi ? w1b : w1a,
                  selhi ? w2b : w2a, selhi ? w3b : w3a);
    }
    SBAR();   // phase fence: keep L2's ds_reads from hoisting into L1
    // ---- L2: mt-pairs -> B3[p] ----
    bf16x8 B3[4];
    #pragma unroll
    for (int p = 0; p < 4; ++p) {
      f32x4 a0 = (f32x4){0.f, 0.f, 0.f, 0.f}, a1 = (f32x4){0.f, 0.f, 0.f, 0.f};
      #pragma unroll
      for (int kt = 0; kt < 8; ++kt) {
        bf16x8 wA = *(const bf16x8*)(w2p + (2 * p) * 4224 + kt * 32);
        bf16x8 wB = *(const bf16x8*)(w2p + (2 * p + 1) * 4224 + kt * 32);
        a0 = __builtin_amdgcn_mfma_f32_16x16x32_bf16(wA, B2[kt], a0, 0, 0, 0);
        a1 = __builtin_amdgcn_mfma_f32_16x16x32_bf16(wB, B2[kt], a1, 0, 0, 0);
      }
      float4 cb0 = *(const float4*)(sC + 256 + 16 * (2 * p) + 4 * lg);
      float4 cb1 = *(const float4*)(sC + 256 + 16 * (2 * p + 1) + 4 * lg);
      unsigned q0 = pk2(lrelu(a0[0] + cb0.x), lrelu(a0[1] + cb0.y));
      unsigned q1 = pk2(lrelu(a0[2] + cb0.z), lrelu(a0[3] + cb0.w));
      unsigned q2 = pk2(lrelu(a1[0] + cb1.x), lrelu(a1[1] + cb1.y));
      unsigned q3 = pk2(lrelu(a1[2] + cb1.z), lrelu(a1[3] + cb1.w));
      unsigned w0a = SHF(q0, srcLo), w0b = SHF(q2, srcLo);
      unsigned w1a = SHF(q1, srcLo), w1b = SHF(q3, srcLo);
      unsigned w2a = SHF(q0, srcHi), w2b = SHF(q2, srcHi);
      unsigned w3a = SHF(q1, srcHi), w3b = SHF(q3, srcHi);
      B3[p] = mk8(selhi ? w0b : w0a, selhi ? w1b : w1a,
                  selhi ? w2b : w2a, selhi ? w3b : w3a);
    }
    SBAR();   // phase fence
    // ---- prefetch next 16-row group: issue here, consume at loop bottom.
    //      tA is live only across L3/L4 (the thin phase), not across L2.
    int rn = r0 + 32768; if (rn >= NN) rn = r0;   // last iter: dummy reload
    float4 tA[8];
    {
      const float4* p = (const float4*)(enc + (size_t)(rn + lr) * 128);
      #pragma unroll
      for (int kt = 0; kt < 4; ++kt) {
        tA[2 * kt]     = p[kt * 8 + lg * 2];
        tA[2 * kt + 1] = p[kt * 8 + lg * 2 + 1];
      }
    }
    SBAR();   // pin the load-issue position (do not sink into L3)
    // ---- L3 (mt-pairs) + L4 epilogue folded into W4 dot ----
    float dot = 0.f;
    #pragma unroll
    for (int p = 0; p < 2; ++p) {
      f32x4 a0 = (f32x4){0.f, 0.f, 0.f, 0.f}, a1 = (f32x4){0.f, 0.f, 0.f, 0.f};
      #pragma unroll
      for (int kt = 0; kt < 4; ++kt) {
        bf16x8 wA = *(const bf16x8*)(w3p + (2 * p) * 2176 + kt * 32);
        bf16x8 wB = *(const bf16x8*)(w3p + (2 * p + 1) * 2176 + kt * 32);
        a0 = __builtin_amdgcn_mfma_f32_16x16x32_bf16(wA, B3[kt], a0, 0, 0, 0);
        a1 = __builtin_amdgcn_mfma_f32_16x16x32_bf16(wB, B3[kt], a1, 0, 0, 0);
      }
      float4 cb0  = *(const float4*)(sC + 384 + 16 * (2 * p) + 4 * lg);
      float4 cb1  = *(const float4*)(sC + 384 + 16 * (2 * p + 1) + 4 * lg);
      float4 w4v0 = *(const float4*)(sC + 448 + 16 * (2 * p) + 4 * lg);
      float4 w4v1 = *(const float4*)(sC + 448 + 16 * (2 * p + 1) + 4 * lg);
      dot += lrelu(a0[0] + cb0.x) * w4v0.x + lrelu(a0[1] + cb0.y) * w4v0.y
           + lrelu(a0[2] + cb0.z) * w4v0.z + lrelu(a0[3] + cb0.w) * w4v0.w;
      dot += lrelu(a1[0] + cb1.x) * w4v1.x + lrelu(a1[1] + cb1.y) * w4v1.y
           + lrelu(a1[2] + cb1.z) * w4v1.z + lrelu(a1[3] + cb1.w) * w4v1.w;
    }
    dot += __shfl_xor(dot, 16, 64);
    dot += __shfl_xor(dot, 32, 64);
    float ev = expf(dot + sC[512]);
    if (lg == 0) eL[r0 + lr] = ev;
    es += ev;                        // 4x duplicated across lg, scaled at the end
    // ---- convert prefetched rows -> B1 for next iteration ----
    #pragma unroll
    for (int kt = 0; kt < 4; ++kt) {
      float4 f0 = tA[2 * kt], f1 = tA[2 * kt + 1];
      bf16x8 a;
      a[0] = (__bf16)f0.x; a[1] = (__bf16)f0.y; a[2] = (__bf16)f0.z; a[3] = (__bf16)f0.w;
      a[4] = (__bf16)f1.x; a[5] = (__bf16)f1.y; a[6] = (__bf16)f1.z; a[7] = (__bf16)f1.w;
      B1[kt] = a;
    }
  }
  // wave-wide partial softmax denominator (deterministic: one slot per wave)
  #pragma unroll
  for (int off = 1; off < 64; off <<= 1) es += __shfl_xor(es, off, 64);
  if (lane == 0) psum[wid] = 0.25f * es;
}

// ---------------- final reduce + normalize ----------------
__global__ __launch_bounds__(256) void k_finalsum(const float* __restrict__ psum,
                                                  float* __restrict__ scal)
{
  const int tid = threadIdx.x;
  float s = 0.f;
  #pragma unroll
  for (int k = 0; k < 8; ++k) s += psum[tid + k * 256];
  #pragma unroll
  for (int off = 1; off < 64; off <<= 1) s += __shfl_xor(s, off, 64);
  __shared__ float sr[4];
  if ((tid & 63) == 0) sr[tid >> 6] = s;
  __syncthreads();
  if (tid == 0) scal[0] = 1.f / (sr[0] + sr[1] + sr[2] + sr[3]);
}

__global__ __launch_bounds__(256) void k_norm(const float* __restrict__ eL,
                                              const float* __restrict__ scal,
                                              float* __restrict__ out)
{
  const float inv = scal[0];
  const int i = blockIdx.x * 256 + threadIdx.x;
  if (i < NN / 4) {
    float4 v = ((const float4*)eL)[i];
    float4 o = {v.x * inv, v.y * inv, v.z * inv, v.w * inv};
    ((float4*)out)[i] = o;
  }
}

extern "C" void kernel_launch(void* const* d_in, const int* in_sizes, int n_in,
                              void* d_out, int out_size, void* d_ws, size_t ws_size,
                              hipStream_t stream) {
  const float* enc = (const float*)d_in[0];
  const int*   cs  = (const int*)d_in[1];
  const float* W1  = (const float*)d_in[2];
  const float* b1  = (const float*)d_in[3];
  const float* W2  = (const float*)d_in[4];
  const float* b2  = (const float*)d_in[5];
  const float* W3  = (const float*)d_in[6];
  const float* b3  = (const float*)d_in[7];
  const float* W4  = (const float*)d_in[8];
  const float* b4  = (const float*)d_in[9];
  float* out = (float*)d_out;

  char* ws = (char*)d_ws;
  float* mu_in  = (float*)(ws + 0);        // 512 B
  float* mu_not = (float*)(ws + 512);      // 512 B
  float* psum   = (float*)(ws + 2048);     // 2048 floats = 8 KB
  float* scal   = (float*)(ws + 10240);    // 4 B
  float* red2   = (float*)(ws + 16384);    // 64*256*4 = 64 KB
  float* eLbuf  = (float*)(ws + 131072);   // 2 MB (exp(logit) per row)
  // colmax partials alias the eL region: live only BEFORE k_mlp writes eL.
  float* partials = (float*)(ws + 131072); // 2000*256*4 = 2,048,000 B

  k_colmax<<<dim3(NBLK_CM), dim3(256), 0, stream>>>(enc, cs, partials);
  k_red1<<<dim3(64), dim3(256), 0, stream>>>(partials, red2);
  k_red2<<<dim3(1), dim3(1024), 0, stream>>>(red2, mu_in, mu_not);
  k_mlp<<<dim3(256), dim3(512), 0, stream>>>(enc, W1, b1, W2, b2, W3, b3, W4, b4,
                                             mu_in, mu_not, eLbuf, psum);
  k_finalsum<<<dim3(1), dim3(256), 0, stream>>>(psum, scal);
  k_norm<<<dim3(489), dim3(256), 0, stream>>>(eLbuf, scal, out);
}

// Round 9
// 182.898 us; speedup vs baseline: 1.8397x; 1.0534x over previous
//
#include <hip/hip_runtime.h>
#include <hip/hip_bf16.h>

#define NN 500000
#define NBLK_CM 2000   // colmax blocks: 2000 * 250 rows = 500,000 exact
// feats = [mu_in(128) | mu_not(128) | enc(128)]; H1=256, H2=128, H3=64

typedef unsigned short ushort_t;
typedef __attribute__((ext_vector_type(8))) __bf16 bf16x8;
typedef __attribute__((ext_vector_type(2))) __bf16 bf16x2;
typedef __attribute__((ext_vector_type(4))) float f32x4;
typedef __attribute__((ext_vector_type(4))) unsigned uint4v;

__device__ inline ushort_t f2bf(float f) {
  unsigned u = __builtin_bit_cast(unsigned, f);
  return (ushort_t)((u + 0x7FFFu + ((u >> 16) & 1u)) >> 16);
}
__device__ inline float lrelu(float v) { return fmaxf(v, 0.f) + 0.01f * fminf(v, 0.f); }
__device__ inline unsigned pk2(float lo, float hi) {
  bf16x2 v; v[0] = (__bf16)lo; v[1] = (__bf16)hi;
  return __builtin_bit_cast(unsigned, v);
}
__device__ inline bf16x8 mk8(unsigned w0, unsigned w1, unsigned w2, unsigned w3) {
  uint4v u; u.x = w0; u.y = w1; u.z = w2; u.w = w3;
  return __builtin_bit_cast(bf16x8, u);
}
#define SHF_X(v, m) ((unsigned)__shfl_xor((int)(v), (m), 64))
#define SBAR() __builtin_amdgcn_sched_barrier(0)

// 4-lane-group transpose (lanes {lr, lr+16, lr+32, lr+48}) as a 2-stage xor
// butterfly: replaces 8 ds_bpermute with 4 ds ops + cndmasks (VALU has headroom;
// LDS pipe is the bottleneck). Produces the SAME permutation as the old
// srcLo/srcHi bpermute code -- bit-identical results.
__device__ inline void bfly4(unsigned q0, unsigned q1, unsigned q2, unsigned q3,
                             bool b0, bool b1,
                             unsigned& w0, unsigned& w1, unsigned& w2, unsigned& w3)
{
  unsigned vA0 = b1 ? q0 : q2, vA1 = b1 ? q1 : q3;   // send elements e1 = !b1
  unsigned eA0 = SHF_X(vA0, 32), eA1 = SHF_X(vA1, 32);
  unsigned s00 = b1 ? eA0 : q0, s01 = b1 ? eA1 : q1; // s[x][j0]: elem (b1,j0) of lane (x,b0)
  unsigned s10 = b1 ? q2 : eA0, s11 = b1 ? q3 : eA1;
  unsigned vB0 = b0 ? s00 : s10, vB1 = b0 ? s01 : s11;
  unsigned eB0 = SHF_X(vB0, 16), eB1 = SHF_X(vB1, 16);
  w0 = b0 ? eB0 : s00; w1 = b0 ? eB1 : s01;
  w2 = b0 ? s10 : eB0; w3 = b0 ? s11 : eB1;
}

// ---------------- K_colmax: masked per-column max -> per-block partials (NO atomics) ----
__global__ __launch_bounds__(256) void k_colmax(
    const float* __restrict__ enc, const int* __restrict__ cs,
    float* __restrict__ partials)            // [NBLK_CM][256]: in(128)|not(128)
{
  __shared__ float4 s_in[256], s_not[256];
  const int tid = threadIdx.x;
  const int c4 = tid & 31;    // float4-column 0..31
  const int rs = tid >> 5;    // row slice 0..7
  const long base = (long)blockIdx.x * 250;
  float4 mi = {0.f, 0.f, 0.f, 0.f}, mn = {0.f, 0.f, 0.f, 0.f};
  const float4* e4 = (const float4*)enc;
  #pragma unroll 4
  for (int it = 0; it < 32; ++it) {        // 8 slices x 32 = 256 rows >= 250 (guarded)
    long r = base + rs + 8L * it;
    if (r < base + 250 && r < NN) {
      float4 v = e4[r * 32 + c4];
      bool ins = cs[r] > 0;
      mi.x = fmaxf(mi.x, ins ? v.x : 0.f); mi.y = fmaxf(mi.y, ins ? v.y : 0.f);
      mi.z = fmaxf(mi.z, ins ? v.z : 0.f); mi.w = fmaxf(mi.w, ins ? v.w : 0.f);
      mn.x = fmaxf(mn.x, ins ? 0.f : v.x); mn.y = fmaxf(mn.y, ins ? 0.f : v.y);
      mn.z = fmaxf(mn.z, ins ? 0.f : v.z); mn.w = fmaxf(mn.w, ins ? 0.f : v.w);
    }
  }
  s_in[tid] = mi; s_not[tid] = mn;
  __syncthreads();
  if (tid < 32) {
    for (int j = 1; j < 8; ++j) {
      float4 a = s_in[j * 32 + tid], b = s_not[j * 32 + tid];
      mi.x = fmaxf(mi.x, a.x); mi.y = fmaxf(mi.y, a.y);
      mi.z = fmaxf(mi.z, a.z); mi.w = fmaxf(mi.w, a.w);
      mn.x = fmaxf(mn.x, b.x); mn.y = fmaxf(mn.y, b.y);
      mn.z = fmaxf(mn.z, b.z); mn.w = fmaxf(mn.w, b.w);
    }
    float* po = partials + (size_t)blockIdx.x * 256;
    ((float4*)po)[tid] = mi;           // cols 4t..4t+3 of mu_in partial
    ((float4*)(po + 128))[tid] = mn;   // mu_not partial
  }
}

// ---------------- K_red1: 64 blocks fold 2000 partial rows -> red2[64][256] ------------
__global__ __launch_bounds__(256) void k_red1(
    const float* __restrict__ partials, float* __restrict__ red2)
{
  const int tid = threadIdx.x, b = blockIdx.x;
  float m = 0.f;               // identity: masked max >= 0
  #pragma unroll 8
  for (int row = b; row < NBLK_CM; row += 64)
    m = fmaxf(m, partials[(size_t)row * 256 + tid]);
  red2[b * 256 + tid] = m;
}

// ---------------- K_red2: 1 block folds red2[64][256] -> mu_in/mu_not ------------------
__global__ __launch_bounds__(1024) void k_red2(
    const float* __restrict__ red2,
    float* __restrict__ mu_in, float* __restrict__ mu_not)
{
  __shared__ float sT[1024];
  const int tid = threadIdx.x;
  const int col = tid & 255, sl = tid >> 8;     // 4 slices x 16 rows
  float m = 0.f;
  #pragma unroll
  for (int j = 0; j < 16; ++j)
    m = fmaxf(m, red2[(sl * 16 + j) * 256 + col]);
  sT[tid] = m;
  __syncthreads();
  if (tid < 256) {
    m = fmaxf(fmaxf(sT[tid], sT[tid + 256]), fmaxf(sT[tid + 512], sT[tid + 768]));
    if (tid < 128) mu_in[tid] = m;
    else           mu_not[tid - 128] = m;
  }
}

// ---------------- K_mlp: persistent, weights LDS-resident, barrier-free loop -------------
// Round-9 changes (LDS-pipe bound at 153 us: 144 b128 reads + 96 bpermutes/iter,
// 2.58e7 bank-conflict cycles from pitch 68 dw == 4 mod 32):
//  (a) weight swizzle: 16B block b of row n stored at b' = (b + 2n) & mask, pitch
//      unpadded (W1 256B, W2 512B, W3 256B rows). Read group (4kt+lg+2lr)&mask tiles
//      all 8 bank-groups exactly 8 lanes each -> conflict-free.
//  (b) layer-handoff butterfly via 2-stage shfl_xor (bfly4): halves DS shuffle ops.
// Everything else identical to round 8 (VGPR 88, zero spill, verified).
__global__ __launch_bounds__(512)
__attribute__((amdgpu_waves_per_eu(2, 2)))
void k_mlp(
    const float* __restrict__ enc,
    const float* __restrict__ W1, const float* __restrict__ b1,
    const float* __restrict__ W2, const float* __restrict__ b2,
    const float* __restrict__ W3, const float* __restrict__ b3,
    const float* __restrict__ W4, const float* __restrict__ b4,
    const float* __restrict__ mu_in, const float* __restrict__ mu_not,
    float* __restrict__ eL, float* __restrict__ psum)
{
  __shared__ ushort_t sW1[256 * 128];   // [n1][swizzled k=e]   65536 B
  __shared__ ushort_t sW2[128 * 256];   // [n2][swizzled k=n1]  65536 B
  __shared__ ushort_t sW3[64 * 128];    // [n3][swizzled k=n2]  16384 B
  __shared__ float sC[520];             // c[256]|b2[128]|b3[64]|W4[64]|b4
  __shared__ float sT[512];             // cvec partials

  const int tid = threadIdx.x;

  // ---- one-time staging: fp32 global -> bf16 LDS, transposed + block-swizzled ----
  for (int idx = tid; idx < 32768; idx += 512) {
    int n = idx & 255, k = idx >> 8;              // n1, e (k<128)
    int bp = ((k >> 3) + 2 * n) & 15;
    sW1[n * 128 + bp * 8 + (k & 7)] = f2bf(W1[(256 + k) * 256 + n]);
  }
  for (int idx = tid; idx < 32768; idx += 512) {
    int n = idx & 127, k = idx >> 7;              // n2, n1 (k<256)
    int bp = ((k >> 3) + 2 * n) & 31;
    sW2[n * 256 + bp * 8 + (k & 7)] = f2bf(W2[k * 128 + n]);
  }
  for (int idx = tid; idx < 8192; idx += 512) {
    int n = idx & 63, k = idx >> 6;               // n3, n2 (k<128)
    int bp = ((k >> 3) + 2 * n) & 15;
    sW3[n * 128 + bp * 8 + (k & 7)] = f2bf(W3[k * 64 + n]);
  }
  if (tid >= 256 && tid < 384) sC[tid] = b2[tid - 256];
  else if (tid >= 384 && tid < 448) sC[tid] = b3[tid - 384];
  else if (tid >= 448) sC[tid] = W4[tid - 448];
  if (tid == 0) sC[512] = b4[0];
  { // inlined cvec: c[j] = b1[j] + mu_in . W1[0:128,j] + mu_not . W1[128:256,j]
    const int j = tid & 255, h = tid >> 8;        // h = 0..1
    float c = h ? 0.f : b1[j];
    #pragma unroll 8
    for (int e = 64 * h; e < 64 * h + 64; ++e) {
      c += mu_in[e]  * W1[e * 256 + j];
      c += mu_not[e] * W1[(128 + e) * 256 + j];
    }
    sT[tid] = c;
  }
  __syncthreads();
  if (tid < 256) sC[tid] = sT[tid] + sT[tid + 256];
  __syncthreads();   // last block-wide barrier

  const int wave = tid >> 6, lane = tid & 63;
  const int lr = lane & 15, lg = lane >> 4;
  const int wid = blockIdx.x * 8 + wave;          // 0..2047
  const bool b0 = lg & 1, b1f = lg & 2;           // butterfly selectors
  const int sw = lg + 2 * lr;                     // swizzle read term

  const ushort_t* w1p = sW1 + lr * 128;           // + mt*2048 + ((4kt+sw)&15)*8
  const ushort_t* w2p = sW2 + lr * 256;           // + mt*4096 + ((4kt+sw)&31)*8
  const ushort_t* w3p = sW3 + lr * 128;           // + mt*2048 + ((4kt+sw)&15)*8

  float es = 0.f;
  bf16x8 B1[4];

  // preload + convert first 16-row group (row = wid*16 + lr, always < NN)
  {
    const float4* p = (const float4*)(enc + (size_t)(wid * 16 + lr) * 128);
    #pragma unroll
    for (int kt = 0; kt < 4; ++kt) {
      float4 f0 = p[kt * 8 + lg * 2], f1 = p[kt * 8 + lg * 2 + 1];
      bf16x8 a;
      a[0] = (__bf16)f0.x; a[1] = (__bf16)f0.y; a[2] = (__bf16)f0.z; a[3] = (__bf16)f0.w;
      a[4] = (__bf16)f1.x; a[5] = (__bf16)f1.y; a[6] = (__bf16)f1.z; a[7] = (__bf16)f1.w;
      B1[kt] = a;
    }
  }

  for (int r0 = wid * 16; r0 < NN; r0 += 32768) {
    // ---- L1: mt-pairs with immediate epilogue + bfly4 -> B2[p] ----
    bf16x8 B2[8];
    #pragma unroll
    for (int p = 0; p < 8; ++p) {
      f32x4 a0 = (f32x4){0.f, 0.f, 0.f, 0.f}, a1 = (f32x4){0.f, 0.f, 0.f, 0.f};
      #pragma unroll
      for (int kt = 0; kt < 4; ++kt) {
        bf16x8 wA = *(const bf16x8*)(w1p + (2 * p) * 2048 + (((4 * kt + sw) & 15) << 3));
        bf16x8 wB = *(const bf16x8*)(w1p + (2 * p + 1) * 2048 + (((4 * kt + sw) & 15) << 3));
        a0 = __builtin_amdgcn_mfma_f32_16x16x32_bf16(wA, B1[kt], a0, 0, 0, 0);
        a1 = __builtin_amdgcn_mfma_f32_16x16x32_bf16(wB, B1[kt], a1, 0, 0, 0);
      }
      float4 cb0 = *(const float4*)(sC + 16 * (2 * p) + 4 * lg);
      float4 cb1 = *(const float4*)(sC + 16 * (2 * p + 1) + 4 * lg);
      unsigned q0 = pk2(lrelu(a0[0] + cb0.x), lrelu(a0[1] + cb0.y));
      unsigned q1 = pk2(lrelu(a0[2] + cb0.z), lrelu(a0[3] + cb0.w));
      unsigned q2 = pk2(lrelu(a1[0] + cb1.x), lrelu(a1[1] + cb1.y));
      unsigned q3 = pk2(lrelu(a1[2] + cb1.z), lrelu(a1[3] + cb1.w));
      unsigned w0, w1, w2, w3;
      bfly4(q0, q1, q2, q3, b0, b1f, w0, w1, w2, w3);
      B2[p] = mk8(w0, w1, w2, w3);
    }
    SBAR();   // phase fence: keep L2's ds_reads from hoisting into L1
    // ---- L2: mt-pairs -> B3[p] ----
    bf16x8 B3[4];
    #pragma unroll
    for (int p = 0; p < 4; ++p) {
      f32x4 a0 = (f32x4){0.f, 0.f, 0.f, 0.f}, a1 = (f32x4){0.f, 0.f, 0.f, 0.f};
      #pragma unroll
      for (int kt = 0; kt < 8; ++kt) {
        bf16x8 wA = *(const bf16x8*)(w2p + (2 * p) * 4096 + (((4 * kt + sw) & 31) << 3));
        bf16x8 wB = *(const bf16x8*)(w2p + (2 * p + 1) * 4096 + (((4 * kt + sw) & 31) << 3));
        a0 = __builtin_amdgcn_mfma_f32_16x16x32_bf16(wA, B2[kt], a0, 0, 0, 0);
        a1 = __builtin_amdgcn_mfma_f32_16x16x32_bf16(wB, B2[kt], a1, 0, 0, 0);
      }
      float4 cb0 = *(const float4*)(sC + 256 + 16 * (2 * p) + 4 * lg);
      float4 cb1 = *(const float4*)(sC + 256 + 16 * (2 * p + 1) + 4 * lg);
      unsigned q0 = pk2(lrelu(a0[0] + cb0.x), lrelu(a0[1] + cb0.y));
      unsigned q1 = pk2(lrelu(a0[2] + cb0.z), lrelu(a0[3] + cb0.w));
      unsigned q2 = pk2(lrelu(a1[0] + cb1.x), lrelu(a1[1] + cb1.y));
      unsigned q3 = pk2(lrelu(a1[2] + cb1.z), lrelu(a1[3] + cb1.w));
      unsigned w0, w1, w2, w3;
      bfly4(q0, q1, q2, q3, b0, b1f, w0, w1, w2, w3);
      B3[p] = mk8(w0, w1, w2, w3);
    }
    SBAR();   // phase fence
    // ---- prefetch next 16-row group: issue here, consume at loop bottom ----
    int rn = r0 + 32768; if (rn >= NN) rn = r0;   // last iter: dummy reload
    float4 tA[8];
    {
      const float4* p = (const float4*)(enc + (size_t)(rn + lr) * 128);
      #pragma unroll
      for (int kt = 0; kt < 4; ++kt) {
        tA[2 * kt]     = p[kt * 8 + lg * 2];
        tA[2 * kt + 1] = p[kt * 8 + lg * 2 + 1];
      }
    }
    SBAR();   // pin the load-issue position (do not sink into L3)
    // ---- L3 (mt-pairs) + L4 epilogue folded into W4 dot ----
    float dot = 0.f;
    #pragma unroll
    for (int p = 0; p < 2; ++p) {
      f32x4 a0 = (f32x4){0.f, 0.f, 0.f, 0.f}, a1 = (f32x4){0.f, 0.f, 0.f, 0.f};
      #pragma unroll
      for (int kt = 0; kt < 4; ++kt) {
        bf16x8 wA = *(const bf16x8*)(w3p + (2 * p) * 2048 + (((4 * kt + sw) & 15) << 3));
        bf16x8 wB = *(const bf16x8*)(w3p + (2 * p + 1) * 2048 + (((4 * kt + sw) & 15) << 3));
        a0 = __builtin_amdgcn_mfma_f32_16x16x32_bf16(wA, B3[kt], a0, 0, 0, 0);
        a1 = __builtin_amdgcn_mfma_f32_16x16x32_bf16(wB, B3[kt], a1, 0, 0, 0);
      }
      float4 cb0  = *(const float4*)(sC + 384 + 16 * (2 * p) + 4 * lg);
      float4 cb1  = *(const float4*)(sC + 384 + 16 * (2 * p + 1) + 4 * lg);
      float4 w4v0 = *(const float4*)(sC + 448 + 16 * (2 * p) + 4 * lg);
      float4 w4v1 = *(const float4*)(sC + 448 + 16 * (2 * p + 1) + 4 * lg);
      dot += lrelu(a0[0] + cb0.x) * w4v0.x + lrelu(a0[1] + cb0.y) * w4v0.y
           + lrelu(a0[2] + cb0.z) * w4v0.z + lrelu(a0[3] + cb0.w) * w4v0.w;
      dot += lrelu(a1[0] + cb1.x) * w4v1.x + lrelu(a1[1] + cb1.y) * w4v1.y
           + lrelu(a1[2] + cb1.z) * w4v1.z + lrelu(a1[3] + cb1.w) * w4v1.w;
    }
    dot += __shfl_xor(dot, 16, 64);
    dot += __shfl_xor(dot, 32, 64);
    float ev = expf(dot + sC[512]);
    if (lg == 0) eL[r0 + lr] = ev;
    es += ev;                        // 4x duplicated across lg, scaled at the end
    // ---- convert prefetched rows -> B1 for next iteration ----
    #pragma unroll
    for (int kt = 0; kt < 4; ++kt) {
      float4 f0 = tA[2 * kt], f1 = tA[2 * kt + 1];
      bf16x8 a;
      a[0] = (__bf16)f0.x; a[1] = (__bf16)f0.y; a[2] = (__bf16)f0.z; a[3] = (__bf16)f0.w;
      a[4] = (__bf16)f1.x; a[5] = (__bf16)f1.y; a[6] = (__bf16)f1.z; a[7] = (__bf16)f1.w;
      B1[kt] = a;
    }
  }
  // wave-wide partial softmax denominator (deterministic: one slot per wave)
  #pragma unroll
  for (int off = 1; off < 64; off <<= 1) es += __shfl_xor(es, off, 64);
  if (lane == 0) psum[wid] = 0.25f * es;
}

// ---------------- final reduce + normalize ----------------
__global__ __launch_bounds__(256) void k_finalsum(const float* __restrict__ psum,
                                                  float* __restrict__ scal)
{
  const int tid = threadIdx.x;
  float s = 0.f;
  #pragma unroll
  for (int k = 0; k < 8; ++k) s += psum[tid + k * 256];
  #pragma unroll
  for (int off = 1; off < 64; off <<= 1) s += __shfl_xor(s, off, 64);
  __shared__ float sr[4];
  if ((tid & 63) == 0) sr[tid >> 6] = s;
  __syncthreads();
  if (tid == 0) scal[0] = 1.f / (sr[0] + sr[1] + sr[2] + sr[3]);
}

__global__ __launch_bounds__(256) void k_norm(const float* __restrict__ eL,
                                              const float* __restrict__ scal,
                                              float* __restrict__ out)
{
  const float inv = scal[0];
  const int i = blockIdx.x * 256 + threadIdx.x;
  if (i < NN / 4) {
    float4 v = ((const float4*)eL)[i];
    float4 o = {v.x * inv, v.y * inv, v.z * inv, v.w * inv};
    ((float4*)out)[i] = o;
  }
}

extern "C" void kernel_launch(void* const* d_in, const int* in_sizes, int n_in,
                              void* d_out, int out_size, void* d_ws, size_t ws_size,
                              hipStream_t stream) {
  const float* enc = (const float*)d_in[0];
  const int*   cs  = (const int*)d_in[1];
  const float* W1  = (const float*)d_in[2];
  const float* b1  = (const float*)d_in[3];
  const float* W2  = (const float*)d_in[4];
  const float* b2  = (const float*)d_in[5];
  const float* W3  = (const float*)d_in[6];
  const float* b3  = (const float*)d_in[7];
  const float* W4  = (const float*)d_in[8];
  const float* b4  = (const float*)d_in[9];
  float* out = (float*)d_out;

  char* ws = (char*)d_ws;
  float* mu_in  = (float*)(ws + 0);        // 512 B
  float* mu_not = (float*)(ws + 512);      // 512 B
  float* psum   = (float*)(ws + 2048);     // 2048 floats = 8 KB
  float* scal   = (float*)(ws + 10240);    // 4 B
  float* red2   = (float*)(ws + 16384);    // 64*256*4 = 64 KB
  float* eLbuf  = (float*)(ws + 131072);   // 2 MB (exp(logit) per row)
  // colmax partials alias the eL region: live only BEFORE k_mlp writes eL.
  float* partials = (float*)(ws + 131072); // 2000*256*4 = 2,048,000 B

  k_colmax<<<dim3(NBLK_CM), dim3(256), 0, stream>>>(enc, cs, partials);
  k_red1<<<dim3(64), dim3(256), 0, stream>>>(partials, red2);
  k_red2<<<dim3(1), dim3(1024), 0, stream>>>(red2, mu_in, mu_not);
  k_mlp<<<dim3(256), dim3(512), 0, stream>>>(enc, W1, b1, W2, b2, W3, b3, W4, b4,
                                             mu_in, mu_not, eLbuf, psum);
  k_finalsum<<<dim3(1), dim3(256), 0, stream>>>(psum, scal);
  k_norm<<<dim3(489), dim3(256), 0, stream>>>(eLbuf, scal, out);
}

// Round 10
// 171.829 us; speedup vs baseline: 1.9582x; 1.0644x over previous
//
#include <hip/hip_runtime.h>
#include <hip/hip_bf16.h>

#define NN 500000
#define NBLK_CM 2000   // colmax blocks: 2000 * 250 rows = 500,000 exact
// feats = [mu_in(128) | mu_not(128) | enc(128)]; H1=256, H2=128, H3=64

typedef unsigned short ushort_t;
typedef __attribute__((ext_vector_type(8))) __bf16 bf16x8;
typedef __attribute__((ext_vector_type(2))) __bf16 bf16x2;
typedef __attribute__((ext_vector_type(4))) float f32x4;
typedef __attribute__((ext_vector_type(4))) unsigned uint4v;

__device__ inline ushort_t f2bf(float f) {
  unsigned u = __builtin_bit_cast(unsigned, f);
  return (ushort_t)((u + 0x7FFFu + ((u >> 16) & 1u)) >> 16);
}
__device__ inline float lrelu(float v) { return fmaxf(v, 0.f) + 0.01f * fminf(v, 0.f); }
__device__ inline unsigned pk2(float lo, float hi) {
  bf16x2 v; v[0] = (__bf16)lo; v[1] = (__bf16)hi;
  return __builtin_bit_cast(unsigned, v);
}
__device__ inline bf16x8 mk8(unsigned w0, unsigned w1, unsigned w2, unsigned w3) {
  uint4v u; u.x = w0; u.y = w1; u.z = w2; u.w = w3;
  return __builtin_bit_cast(bf16x8, u);
}
#define SHF_X(v, m) ((unsigned)__shfl_xor((int)(v), (m), 64))
#define SBAR() __builtin_amdgcn_sched_barrier(0)

// 4-lane-group transpose (lanes {lr, lr+16, lr+32, lr+48}) as a 2-stage xor
// butterfly -- bit-identical to the original ds_bpermute version (verified r9).
__device__ inline void bfly4(unsigned q0, unsigned q1, unsigned q2, unsigned q3,
                             bool b0, bool b1,
                             unsigned& w0, unsigned& w1, unsigned& w2, unsigned& w3)
{
  unsigned vA0 = b1 ? q0 : q2, vA1 = b1 ? q1 : q3;
  unsigned eA0 = SHF_X(vA0, 32), eA1 = SHF_X(vA1, 32);
  unsigned s00 = b1 ? eA0 : q0, s01 = b1 ? eA1 : q1;
  unsigned s10 = b1 ? q2 : eA0, s11 = b1 ? q3 : eA1;
  unsigned vB0 = b0 ? s00 : s10, vB1 = b0 ? s01 : s11;
  unsigned eB0 = SHF_X(vB0, 16), eB1 = SHF_X(vB1, 16);
  w0 = b0 ? eB0 : s00; w1 = b0 ? eB1 : s01;
  w2 = b0 ? s10 : eB0; w3 = b0 ? s11 : eB1;
}

// ---------------- K_colmax: masked per-column max -> per-block partials (NO atomics) ----
__global__ __launch_bounds__(256) void k_colmax(
    const float* __restrict__ enc, const int* __restrict__ cs,
    float* __restrict__ partials)            // [NBLK_CM][256]: in(128)|not(128)
{
  __shared__ float4 s_in[256], s_not[256];
  const int tid = threadIdx.x;
  const int c4 = tid & 31;    // float4-column 0..31
  const int rs = tid >> 5;    // row slice 0..7
  const long base = (long)blockIdx.x * 250;
  float4 mi = {0.f, 0.f, 0.f, 0.f}, mn = {0.f, 0.f, 0.f, 0.f};
  const float4* e4 = (const float4*)enc;
  #pragma unroll 4
  for (int it = 0; it < 32; ++it) {        // 8 slices x 32 = 256 rows >= 250 (guarded)
    long r = base + rs + 8L * it;
    if (r < base + 250 && r < NN) {
      float4 v = e4[r * 32 + c4];
      bool ins = cs[r] > 0;
      mi.x = fmaxf(mi.x, ins ? v.x : 0.f); mi.y = fmaxf(mi.y, ins ? v.y : 0.f);
      mi.z = fmaxf(mi.z, ins ? v.z : 0.f); mi.w = fmaxf(mi.w, ins ? v.w : 0.f);
      mn.x = fmaxf(mn.x, ins ? 0.f : v.x); mn.y = fmaxf(mn.y, ins ? 0.f : v.y);
      mn.z = fmaxf(mn.z, ins ? 0.f : v.z); mn.w = fmaxf(mn.w, ins ? 0.f : v.w);
    }
  }
  s_in[tid] = mi; s_not[tid] = mn;
  __syncthreads();
  if (tid < 32) {
    for (int j = 1; j < 8; ++j) {
      float4 a = s_in[j * 32 + tid], b = s_not[j * 32 + tid];
      mi.x = fmaxf(mi.x, a.x); mi.y = fmaxf(mi.y, a.y);
      mi.z = fmaxf(mi.z, a.z); mi.w = fmaxf(mi.w, a.w);
      mn.x = fmaxf(mn.x, b.x); mn.y = fmaxf(mn.y, b.y);
      mn.z = fmaxf(mn.z, b.z); mn.w = fmaxf(mn.w, b.w);
    }
    float* po = partials + (size_t)blockIdx.x * 256;
    ((float4*)po)[tid] = mi;           // cols 4t..4t+3 of mu_in partial
    ((float4*)(po + 128))[tid] = mn;   // mu_not partial
  }
}

// ---------------- K_red1: 64 blocks fold 2000 partial rows -> red2[64][256] ------------
__global__ __launch_bounds__(256) void k_red1(
    const float* __restrict__ partials, float* __restrict__ red2)
{
  const int tid = threadIdx.x, b = blockIdx.x;
  float m = 0.f;               // identity: masked max >= 0
  #pragma unroll 8
  for (int row = b; row < NBLK_CM; row += 64)
    m = fmaxf(m, partials[(size_t)row * 256 + tid]);
  red2[b * 256 + tid] = m;
}

// ---------------- K_red2: 1 block folds red2[64][256] -> mu_in/mu_not ------------------
__global__ __launch_bounds__(1024) void k_red2(
    const float* __restrict__ red2,
    float* __restrict__ mu_in, float* __restrict__ mu_not)
{
  __shared__ float sT[1024];
  const int tid = threadIdx.x;
  const int col = tid & 255, sl = tid >> 8;     // 4 slices x 16 rows
  float m = 0.f;
  #pragma unroll
  for (int j = 0; j < 16; ++j)
    m = fmaxf(m, red2[(sl * 16 + j) * 256 + col]);
  sT[tid] = m;
  __syncthreads();
  if (tid < 256) {
    m = fmaxf(fmaxf(sT[tid], sT[tid + 256]), fmaxf(sT[tid + 512], sT[tid + 768]));
    if (tid < 128) mu_in[tid] = m;
    else           mu_not[tid - 128] = m;
  }
}

// ---------------- K_mlp: persistent, weights LDS-resident, barrier-free loop -------------
// Round-10: 32 rows/wave-iter (row-groups a,b) -- each weight ds_read_b128 feeds TWO
// MFMAs, halving DS ops/row (the LDS pipe is the bottleneck: 144 reads + 96 shfl/iter).
// This is round-3's idea, which failed ONLY on the 128-reg budget; the proven recipe
// (plain launch_bounds(512) + amdgpu_waves_per_eu(2,2) -> 256-reg budget) is retained.
// Live-set audit: B1 dead during L2/L3; peak ~140 regs. Spill tripwire: WRITE_SIZE.
__global__ __launch_bounds__(512)
__attribute__((amdgpu_waves_per_eu(2, 2)))
void k_mlp(
    const float* __restrict__ enc,
    const float* __restrict__ W1, const float* __restrict__ b1,
    const float* __restrict__ W2, const float* __restrict__ b2,
    const float* __restrict__ W3, const float* __restrict__ b3,
    const float* __restrict__ W4, const float* __restrict__ b4,
    const float* __restrict__ mu_in, const float* __restrict__ mu_not,
    float* __restrict__ eL, float* __restrict__ psum)
{
  __shared__ ushort_t sW1[256 * 128];   // [n1][swizzled k=e]   65536 B
  __shared__ ushort_t sW2[128 * 256];   // [n2][swizzled k=n1]  65536 B
  __shared__ ushort_t sW3[64 * 128];    // [n3][swizzled k=n2]  16384 B
  __shared__ float sC[520];             // c[256]|b2[128]|b3[64]|W4[64]|b4
  __shared__ float sT[512];             // cvec partials

  const int tid = threadIdx.x;

  // ---- one-time staging: fp32 global -> bf16 LDS, transposed + block-swizzled ----
  for (int idx = tid; idx < 32768; idx += 512) {
    int n = idx & 255, k = idx >> 8;              // n1, e (k<128)
    int bp = ((k >> 3) + 2 * n) & 15;
    sW1[n * 128 + bp * 8 + (k & 7)] = f2bf(W1[(256 + k) * 256 + n]);
  }
  for (int idx = tid; idx < 32768; idx += 512) {
    int n = idx & 127, k = idx >> 7;              // n2, n1 (k<256)
    int bp = ((k >> 3) + 2 * n) & 31;
    sW2[n * 256 + bp * 8 + (k & 7)] = f2bf(W2[k * 128 + n]);
  }
  for (int idx = tid; idx < 8192; idx += 512) {
    int n = idx & 63, k = idx >> 6;               // n3, n2 (k<128)
    int bp = ((k >> 3) + 2 * n) & 15;
    sW3[n * 128 + bp * 8 + (k & 7)] = f2bf(W3[k * 64 + n]);
  }
  if (tid >= 256 && tid < 384) sC[tid] = b2[tid - 256];
  else if (tid >= 384 && tid < 448) sC[tid] = b3[tid - 384];
  else if (tid >= 448) sC[tid] = W4[tid - 448];
  if (tid == 0) sC[512] = b4[0];
  { // inlined cvec: c[j] = b1[j] + mu_in . W1[0:128,j] + mu_not . W1[128:256,j]
    const int j = tid & 255, h = tid >> 8;        // h = 0..1
    float c = h ? 0.f : b1[j];
    #pragma unroll 8
    for (int e = 64 * h; e < 64 * h + 64; ++e) {
      c += mu_in[e]  * W1[e * 256 + j];
      c += mu_not[e] * W1[(128 + e) * 256 + j];
    }
    sT[tid] = c;
  }
  __syncthreads();
  if (tid < 256) sC[tid] = sT[tid] + sT[tid + 256];
  __syncthreads();   // last block-wide barrier

  const int wave = tid >> 6, lane = tid & 63;
  const int lr = lane & 15, lg = lane >> 4;
  const int wid = blockIdx.x * 8 + wave;          // 0..2047
  const bool b0 = lg & 1, b1f = lg & 2;           // butterfly selectors
  const int sw = lg + 2 * lr;                     // swizzle read term

  const ushort_t* w1p = sW1 + lr * 128;           // + mt*2048 + ((4kt+sw)&15)*8
  const ushort_t* w2p = sW2 + lr * 256;           // + mt*4096 + ((4kt+sw)&31)*8
  const ushort_t* w3p = sW3 + lr * 128;           // + mt*2048 + ((4kt+sw)&15)*8

  float es = 0.f;
  bf16x8 B1a[4], B1b[4];

  // preload + convert first 32-row group (NN = 32*15625 exact -- never OOB)
  {
    const float4* pa = (const float4*)(enc + (size_t)(wid * 32 + lr) * 128);
    const float4* pb = (const float4*)(enc + (size_t)(wid * 32 + 16 + lr) * 128);
    #pragma unroll
    for (int kt = 0; kt < 4; ++kt) {
      float4 f0 = pa[kt * 8 + lg * 2], f1 = pa[kt * 8 + lg * 2 + 1];
      float4 g0 = pb[kt * 8 + lg * 2], g1 = pb[kt * 8 + lg * 2 + 1];
      bf16x8 a, b;
      a[0] = (__bf16)f0.x; a[1] = (__bf16)f0.y; a[2] = (__bf16)f0.z; a[3] = (__bf16)f0.w;
      a[4] = (__bf16)f1.x; a[5] = (__bf16)f1.y; a[6] = (__bf16)f1.z; a[7] = (__bf16)f1.w;
      b[0] = (__bf16)g0.x; b[1] = (__bf16)g0.y; b[2] = (__bf16)g0.z; b[3] = (__bf16)g0.w;
      b[4] = (__bf16)g1.x; b[5] = (__bf16)g1.y; b[6] = (__bf16)g1.z; b[7] = (__bf16)g1.w;
      B1a[kt] = a; B1b[kt] = b;
    }
  }

  for (int r0 = wid * 32; r0 < NN; r0 += 65536) {
    // ---- L1: mt-pairs; each weight read feeds groups a AND b ----
    bf16x8 B2a[8], B2b[8];
    #pragma unroll
    for (int p = 0; p < 8; ++p) {
      f32x4 aA0 = (f32x4){0.f,0.f,0.f,0.f}, aA1 = (f32x4){0.f,0.f,0.f,0.f};
      f32x4 aB0 = (f32x4){0.f,0.f,0.f,0.f}, aB1 = (f32x4){0.f,0.f,0.f,0.f};
      #pragma unroll
      for (int kt = 0; kt < 4; ++kt) {
        bf16x8 wA = *(const bf16x8*)(w1p + (2 * p) * 2048 + (((4 * kt + sw) & 15) << 3));
        bf16x8 wB = *(const bf16x8*)(w1p + (2 * p + 1) * 2048 + (((4 * kt + sw) & 15) << 3));
        aA0 = __builtin_amdgcn_mfma_f32_16x16x32_bf16(wA, B1a[kt], aA0, 0, 0, 0);
        aA1 = __builtin_amdgcn_mfma_f32_16x16x32_bf16(wB, B1a[kt], aA1, 0, 0, 0);
        aB0 = __builtin_amdgcn_mfma_f32_16x16x32_bf16(wA, B1b[kt], aB0, 0, 0, 0);
        aB1 = __builtin_amdgcn_mfma_f32_16x16x32_bf16(wB, B1b[kt], aB1, 0, 0, 0);
      }
      float4 cb0 = *(const float4*)(sC + 16 * (2 * p) + 4 * lg);
      float4 cb1 = *(const float4*)(sC + 16 * (2 * p + 1) + 4 * lg);
      {
        unsigned q0 = pk2(lrelu(aA0[0] + cb0.x), lrelu(aA0[1] + cb0.y));
        unsigned q1 = pk2(lrelu(aA0[2] + cb0.z), lrelu(aA0[3] + cb0.w));
        unsigned q2 = pk2(lrelu(aA1[0] + cb1.x), lrelu(aA1[1] + cb1.y));
        unsigned q3 = pk2(lrelu(aA1[2] + cb1.z), lrelu(aA1[3] + cb1.w));
        unsigned w0, w1, w2, w3;
        bfly4(q0, q1, q2, q3, b0, b1f, w0, w1, w2, w3);
        B2a[p] = mk8(w0, w1, w2, w3);
      }
      {
        unsigned q0 = pk2(lrelu(aB0[0] + cb0.x), lrelu(aB0[1] + cb0.y));
        unsigned q1 = pk2(lrelu(aB0[2] + cb0.z), lrelu(aB0[3] + cb0.w));
        unsigned q2 = pk2(lrelu(aB1[0] + cb1.x), lrelu(aB1[1] + cb1.y));
        unsigned q3 = pk2(lrelu(aB1[2] + cb1.z), lrelu(aB1[3] + cb1.w));
        unsigned w0, w1, w2, w3;
        bfly4(q0, q1, q2, q3, b0, b1f, w0, w1, w2, w3);
        B2b[p] = mk8(w0, w1, w2, w3);
      }
    }
    SBAR();   // phase fence: keep L2's ds_reads from hoisting into L1
    // ---- L2: mt-pairs -> B3a/B3b ----
    bf16x8 B3a[4], B3b[4];
    #pragma unroll
    for (int p = 0; p < 4; ++p) {
      f32x4 aA0 = (f32x4){0.f,0.f,0.f,0.f}, aA1 = (f32x4){0.f,0.f,0.f,0.f};
      f32x4 aB0 = (f32x4){0.f,0.f,0.f,0.f}, aB1 = (f32x4){0.f,0.f,0.f,0.f};
      #pragma unroll
      for (int kt = 0; kt < 8; ++kt) {
        bf16x8 wA = *(const bf16x8*)(w2p + (2 * p) * 4096 + (((4 * kt + sw) & 31) << 3));
        bf16x8 wB = *(const bf16x8*)(w2p + (2 * p + 1) * 4096 + (((4 * kt + sw) & 31) << 3));
        aA0 = __builtin_amdgcn_mfma_f32_16x16x32_bf16(wA, B2a[kt], aA0, 0, 0, 0);
        aA1 = __builtin_amdgcn_mfma_f32_16x16x32_bf16(wB, B2a[kt], aA1, 0, 0, 0);
        aB0 = __builtin_amdgcn_mfma_f32_16x16x32_bf16(wA, B2b[kt], aB0, 0, 0, 0);
        aB1 = __builtin_amdgcn_mfma_f32_16x16x32_bf16(wB, B2b[kt], aB1, 0, 0, 0);
      }
      float4 cb0 = *(const float4*)(sC + 256 + 16 * (2 * p) + 4 * lg);
      float4 cb1 = *(const float4*)(sC + 256 + 16 * (2 * p + 1) + 4 * lg);
      {
        unsigned q0 = pk2(lrelu(aA0[0] + cb0.x), lrelu(aA0[1] + cb0.y));
        unsigned q1 = pk2(lrelu(aA0[2] + cb0.z), lrelu(aA0[3] + cb0.w));
        unsigned q2 = pk2(lrelu(aA1[0] + cb1.x), lrelu(aA1[1] + cb1.y));
        unsigned q3 = pk2(lrelu(aA1[2] + cb1.z), lrelu(aA1[3] + cb1.w));
        unsigned w0, w1, w2, w3;
        bfly4(q0, q1, q2, q3, b0, b1f, w0, w1, w2, w3);
        B3a[p] = mk8(w0, w1, w2, w3);
      }
      {
        unsigned q0 = pk2(lrelu(aB0[0] + cb0.x), lrelu(aB0[1] + cb0.y));
        unsigned q1 = pk2(lrelu(aB0[2] + cb0.z), lrelu(aB0[3] + cb0.w));
        unsigned q2 = pk2(lrelu(aB1[0] + cb1.x), lrelu(aB1[1] + cb1.y));
        unsigned q3 = pk2(lrelu(aB1[2] + cb1.z), lrelu(aB1[3] + cb1.w));
        unsigned w0, w1, w2, w3;
        bfly4(q0, q1, q2, q3, b0, b1f, w0, w1, w2, w3);
        B3b[p] = mk8(w0, w1, w2, w3);
      }
    }
    SBAR();   // phase fence
    // ---- prefetch next 32-row group (thin phase; consumed at loop bottom) ----
    int rn = r0 + 65536; if (rn >= NN) rn = r0;   // last iter: dummy reload
    float4 tA[8], tB[8];
    {
      const float4* pa = (const float4*)(enc + (size_t)(rn + lr) * 128);
      const float4* pb = (const float4*)(enc + (size_t)(rn + 16 + lr) * 128);
      #pragma unroll
      for (int kt = 0; kt < 4; ++kt) {
        tA[2 * kt]     = pa[kt * 8 + lg * 2];
        tA[2 * kt + 1] = pa[kt * 8 + lg * 2 + 1];
        tB[2 * kt]     = pb[kt * 8 + lg * 2];
        tB[2 * kt + 1] = pb[kt * 8 + lg * 2 + 1];
      }
    }
    SBAR();   // pin the load-issue position (do not sink into L3)
    // ---- L3 (mt-pairs) + L4 epilogue folded into W4 dot, both groups ----
    float da = 0.f, db = 0.f;
    #pragma unroll
    for (int p = 0; p < 2; ++p) {
      f32x4 aA0 = (f32x4){0.f,0.f,0.f,0.f}, aA1 = (f32x4){0.f,0.f,0.f,0.f};
      f32x4 aB0 = (f32x4){0.f,0.f,0.f,0.f}, aB1 = (f32x4){0.f,0.f,0.f,0.f};
      #pragma unroll
      for (int kt = 0; kt < 4; ++kt) {
        bf16x8 wA = *(const bf16x8*)(w3p + (2 * p) * 2048 + (((4 * kt + sw) & 15) << 3));
        bf16x8 wB = *(const bf16x8*)(w3p + (2 * p + 1) * 2048 + (((4 * kt + sw) & 15) << 3));
        aA0 = __builtin_amdgcn_mfma_f32_16x16x32_bf16(wA, B3a[kt], aA0, 0, 0, 0);
        aA1 = __builtin_amdgcn_mfma_f32_16x16x32_bf16(wB, B3a[kt], aA1, 0, 0, 0);
        aB0 = __builtin_amdgcn_mfma_f32_16x16x32_bf16(wA, B3b[kt], aB0, 0, 0, 0);
        aB1 = __builtin_amdgcn_mfma_f32_16x16x32_bf16(wB, B3b[kt], aB1, 0, 0, 0);
      }
      float4 cb0  = *(const float4*)(sC + 384 + 16 * (2 * p) + 4 * lg);
      float4 cb1  = *(const float4*)(sC + 384 + 16 * (2 * p + 1) + 4 * lg);
      float4 w4v0 = *(const float4*)(sC + 448 + 16 * (2 * p) + 4 * lg);
      float4 w4v1 = *(const float4*)(sC + 448 + 16 * (2 * p + 1) + 4 * lg);
      da += lrelu(aA0[0] + cb0.x) * w4v0.x + lrelu(aA0[1] + cb0.y) * w4v0.y
          + lrelu(aA0[2] + cb0.z) * w4v0.z + lrelu(aA0[3] + cb0.w) * w4v0.w;
      da += lrelu(aA1[0] + cb1.x) * w4v1.x + lrelu(aA1[1] + cb1.y) * w4v1.y
          + lrelu(aA1[2] + cb1.z) * w4v1.z + lrelu(aA1[3] + cb1.w) * w4v1.w;
      db += lrelu(aB0[0] + cb0.x) * w4v0.x + lrelu(aB0[1] + cb0.y) * w4v0.y
          + lrelu(aB0[2] + cb0.z) * w4v0.z + lrelu(aB0[3] + cb0.w) * w4v0.w;
      db += lrelu(aB1[0] + cb1.x) * w4v1.x + lrelu(aB1[1] + cb1.y) * w4v1.y
          + lrelu(aB1[2] + cb1.z) * w4v1.z + lrelu(aB1[3] + cb1.w) * w4v1.w;
    }
    da += __shfl_xor(da, 16, 64); da += __shfl_xor(da, 32, 64);
    db += __shfl_xor(db, 16, 64); db += __shfl_xor(db, 32, 64);
    float eva = expf(da + sC[512]), evb = expf(db + sC[512]);
    if (lg == 0) { eL[r0 + lr] = eva; eL[r0 + 16 + lr] = evb; }
    es += eva + evb;                 // 4x duplicated across lg, scaled at the end
    // ---- convert prefetched rows -> B1a/B1b for next iteration ----
    #pragma unroll
    for (int kt = 0; kt < 4; ++kt) {
      float4 f0 = tA[2 * kt], f1 = tA[2 * kt + 1];
      float4 g0 = tB[2 * kt], g1 = tB[2 * kt + 1];
      bf16x8 a, b;
      a[0] = (__bf16)f0.x; a[1] = (__bf16)f0.y; a[2] = (__bf16)f0.z; a[3] = (__bf16)f0.w;
      a[4] = (__bf16)f1.x; a[5] = (__bf16)f1.y; a[6] = (__bf16)f1.z; a[7] = (__bf16)f1.w;
      b[0] = (__bf16)g0.x; b[1] = (__bf16)g0.y; b[2] = (__bf16)g0.z; b[3] = (__bf16)g0.w;
      b[4] = (__bf16)g1.x; b[5] = (__bf16)g1.y; b[6] = (__bf16)g1.z; b[7] = (__bf16)g1.w;
      B1a[kt] = a; B1b[kt] = b;
    }
  }
  // wave-wide partial softmax denominator (deterministic: one slot per wave)
  #pragma unroll
  for (int off = 1; off < 64; off <<= 1) es += __shfl_xor(es, off, 64);
  if (lane == 0) psum[wid] = 0.25f * es;
}

// ---------------- final reduce + normalize ----------------
__global__ __launch_bounds__(256) void k_finalsum(const float* __restrict__ psum,
                                                  float* __restrict__ scal)
{
  const int tid = threadIdx.x;
  float s = 0.f;
  #pragma unroll
  for (int k = 0; k < 8; ++k) s += psum[tid + k * 256];
  #pragma unroll
  for (int off = 1; off < 64; off <<= 1) s += __shfl_xor(s, off, 64);
  __shared__ float sr[4];
  if ((tid & 63) == 0) sr[tid >> 6] = s;
  __syncthreads();
  if (tid == 0) scal[0] = 1.f / (sr[0] + sr[1] + sr[2] + sr[3]);
}

__global__ __launch_bounds__(256) void k_norm(const float* __restrict__ eL,
                                              const float* __restrict__ scal,
                                              float* __restrict__ out)
{
  const float inv = scal[0];
  const int i = blockIdx.x * 256 + threadIdx.x;
  if (i < NN / 4) {
    float4 v = ((const float4*)eL)[i];
    float4 o = {v.x * inv, v.y * inv, v.z * inv, v.w * inv};
    ((float4*)out)[i] = o;
  }
}

extern "C" void kernel_launch(void* const* d_in, const int* in_sizes, int n_in,
                              void* d_out, int out_size, void* d_ws, size_t ws_size,
                              hipStream_t stream) {
  const float* enc = (const float*)d_in[0];
  const int*   cs  = (const int*)d_in[1];
  const float* W1  = (const float*)d_in[2];
  const float* b1  = (const float*)d_in[3];
  const float* W2  = (const float*)d_in[4];
  const float* b2  = (const float*)d_in[5];
  const float* W3  = (const float*)d_in[6];
  const float* b3  = (const float*)d_in[7];
  const float* W4  = (const float*)d_in[8];
  const float* b4  = (const float*)d_in[9];
  float* out = (float*)d_out;

  char* ws = (char*)d_ws;
  float* mu_in  = (float*)(ws + 0);        // 512 B
  float* mu_not = (float*)(ws + 512);      // 512 B
  float* psum   = (float*)(ws + 2048);     // 2048 floats = 8 KB
  float* scal   = (float*)(ws + 10240);    // 4 B
  float* red2   = (float*)(ws + 16384);    // 64*256*4 = 64 KB
  float* eLbuf  = (float*)(ws + 131072);   // 2 MB (exp(logit) per row)
  // colmax partials alias the eL region: live only BEFORE k_mlp writes eL.
  float* partials = (float*)(ws + 131072); // 2000*256*4 = 2,048,000 B

  k_colmax<<<dim3(NBLK_CM), dim3(256), 0, stream>>>(enc, cs, partials);
  k_red1<<<dim3(64), dim3(256), 0, stream>>>(partials, red2);
  k_red2<<<dim3(1), dim3(1024), 0, stream>>>(red2, mu_in, mu_not);
  k_mlp<<<dim3(256), dim3(512), 0, stream>>>(enc, W1, b1, W2, b2, W3, b3, W4, b4,
                                             mu_in, mu_not, eLbuf, psum);
  k_finalsum<<<dim3(1), dim3(256), 0, stream>>>(psum, scal);
  k_norm<<<dim3(489), dim3(256), 0, stream>>>(eLbuf, scal, out);
}

// Round 11
// 170.968 us; speedup vs baseline: 1.9681x; 1.0050x over previous
//
#include <hip/hip_runtime.h>
#include <hip/hip_bf16.h>

#define NN 500000
#define NBLK_CM 2000   // colmax blocks: 2000 * 250 rows = 500,000 exact
// feats = [mu_in(128) | mu_not(128) | enc(128)]; H1=256, H2=128, H3=64

typedef unsigned short ushort_t;
typedef __attribute__((ext_vector_type(8))) __bf16 bf16x8;
typedef __attribute__((ext_vector_type(2))) __bf16 bf16x2;
typedef __attribute__((ext_vector_type(4))) float f32x4;
typedef __attribute__((ext_vector_type(4))) unsigned uint4v;

__device__ inline ushort_t f2bf(float f) {
  unsigned u = __builtin_bit_cast(unsigned, f);
  return (ushort_t)((u + 0x7FFFu + ((u >> 16) & 1u)) >> 16);
}
__device__ inline float lrelu(float v) { return fmaxf(v, 0.f) + 0.01f * fminf(v, 0.f); }
__device__ inline unsigned pk2(float lo, float hi) {
  bf16x2 v; v[0] = (__bf16)lo; v[1] = (__bf16)hi;
  return __builtin_bit_cast(unsigned, v);
}
__device__ inline bf16x8 mk8(unsigned w0, unsigned w1, unsigned w2, unsigned w3) {
  uint4v u; u.x = w0; u.y = w1; u.z = w2; u.w = w3;
  return __builtin_bit_cast(bf16x8, u);
}
#define SHF_X(v, m) ((unsigned)__shfl_xor((int)(v), (m), 64))
#define SBAR() __builtin_amdgcn_sched_barrier(0)
#define PRIO(n) __builtin_amdgcn_s_setprio(n)

// 4-lane-group transpose (lanes {lr, lr+16, lr+32, lr+48}) as a 2-stage xor
// butterfly -- bit-identical to the original ds_bpermute version (verified r9).
__device__ inline void bfly4(unsigned q0, unsigned q1, unsigned q2, unsigned q3,
                             bool b0, bool b1,
                             unsigned& w0, unsigned& w1, unsigned& w2, unsigned& w3)
{
  unsigned vA0 = b1 ? q0 : q2, vA1 = b1 ? q1 : q3;
  unsigned eA0 = SHF_X(vA0, 32), eA1 = SHF_X(vA1, 32);
  unsigned s00 = b1 ? eA0 : q0, s01 = b1 ? eA1 : q1;
  unsigned s10 = b1 ? q2 : eA0, s11 = b1 ? q3 : eA1;
  unsigned vB0 = b0 ? s00 : s10, vB1 = b0 ? s01 : s11;
  unsigned eB0 = SHF_X(vB0, 16), eB1 = SHF_X(vB1, 16);
  w0 = b0 ? eB0 : s00; w1 = b0 ? eB1 : s01;
  w2 = b0 ? s10 : eB0; w3 = b0 ? s11 : eB1;
}

// ---------------- K_colmax: masked per-column max -> per-block partials (NO atomics) ----
__global__ __launch_bounds__(256) void k_colmax(
    const float* __restrict__ enc, const int* __restrict__ cs,
    float* __restrict__ partials)            // [NBLK_CM][256]: in(128)|not(128)
{
  __shared__ float4 s_in[256], s_not[256];
  const int tid = threadIdx.x;
  const int c4 = tid & 31;    // float4-column 0..31
  const int rs = tid >> 5;    // row slice 0..7
  const long base = (long)blockIdx.x * 250;
  float4 mi = {0.f, 0.f, 0.f, 0.f}, mn = {0.f, 0.f, 0.f, 0.f};
  const float4* e4 = (const float4*)enc;
  #pragma unroll 4
  for (int it = 0; it < 32; ++it) {        // 8 slices x 32 = 256 rows >= 250 (guarded)
    long r = base + rs + 8L * it;
    if (r < base + 250 && r < NN) {
      float4 v = e4[r * 32 + c4];
      bool ins = cs[r] > 0;
      mi.x = fmaxf(mi.x, ins ? v.x : 0.f); mi.y = fmaxf(mi.y, ins ? v.y : 0.f);
      mi.z = fmaxf(mi.z, ins ? v.z : 0.f); mi.w = fmaxf(mi.w, ins ? v.w : 0.f);
      mn.x = fmaxf(mn.x, ins ? 0.f : v.x); mn.y = fmaxf(mn.y, ins ? 0.f : v.y);
      mn.z = fmaxf(mn.z, ins ? 0.f : v.z); mn.w = fmaxf(mn.w, ins ? 0.f : v.w);
    }
  }
  s_in[tid] = mi; s_not[tid] = mn;
  __syncthreads();
  if (tid < 32) {
    for (int j = 1; j < 8; ++j) {
      float4 a = s_in[j * 32 + tid], b = s_not[j * 32 + tid];
      mi.x = fmaxf(mi.x, a.x); mi.y = fmaxf(mi.y, a.y);
      mi.z = fmaxf(mi.z, a.z); mi.w = fmaxf(mi.w, a.w);
      mn.x = fmaxf(mn.x, b.x); mn.y = fmaxf(mn.y, b.y);
      mn.z = fmaxf(mn.z, b.z); mn.w = fmaxf(mn.w, b.w);
    }
    float* po = partials + (size_t)blockIdx.x * 256;
    ((float4*)po)[tid] = mi;           // cols 4t..4t+3 of mu_in partial
    ((float4*)(po + 128))[tid] = mn;   // mu_not partial
  }
}

// ---------------- K_red1: 64 blocks fold 2000 partial rows -> red2[64][256] ------------
__global__ __launch_bounds__(256) void k_red1(
    const float* __restrict__ partials, float* __restrict__ red2)
{
  const int tid = threadIdx.x, b = blockIdx.x;
  float m = 0.f;               // identity: masked max >= 0
  #pragma unroll 8
  for (int row = b; row < NBLK_CM; row += 64)
    m = fmaxf(m, partials[(size_t)row * 256 + tid]);
  red2[b * 256 + tid] = m;
}

// ---------------- K_red2: 1 block folds red2[64][256] -> mu_in/mu_not ------------------
__global__ __launch_bounds__(1024) void k_red2(
    const float* __restrict__ red2,
    float* __restrict__ mu_in, float* __restrict__ mu_not)
{
  __shared__ float sT[1024];
  const int tid = threadIdx.x;
  const int col = tid & 255, sl = tid >> 8;     // 4 slices x 16 rows
  float m = 0.f;
  #pragma unroll
  for (int j = 0; j < 16; ++j)
    m = fmaxf(m, red2[(sl * 16 + j) * 256 + col]);
  sT[tid] = m;
  __syncthreads();
  if (tid < 256) {
    m = fmaxf(fmaxf(sT[tid], sT[tid + 256]), fmaxf(sT[tid + 512], sT[tid + 768]));
    if (tid < 128) mu_in[tid] = m;
    else           mu_not[tid - 128] = m;
  }
}

// ---------------- K_mlp: persistent, weights LDS-resident, barrier-free loop -------------
// Round-11: (a) DESCENDING row iteration -- colmax just streamed enc (256 MB ~ L3
// capacity); reading most-recently-cached tail first raises the L3 hit rate (r8
// showed FETCH = 127 MB = only 50% hit). Per-row logits bit-identical; only the
// per-wave es summation order changes (denominator perturbation ~1e-7 relative).
// (b) s_setprio(1) around MFMA clusters: waves here are barrier-free/phase-drifted
// (the attn-like regime where setprio pays, not lockstep GEMM). Else identical to r10.
__global__ __launch_bounds__(512)
__attribute__((amdgpu_waves_per_eu(2, 2)))
void k_mlp(
    const float* __restrict__ enc,
    const float* __restrict__ W1, const float* __restrict__ b1,
    const float* __restrict__ W2, const float* __restrict__ b2,
    const float* __restrict__ W3, const float* __restrict__ b3,
    const float* __restrict__ W4, const float* __restrict__ b4,
    const float* __restrict__ mu_in, const float* __restrict__ mu_not,
    float* __restrict__ eL, float* __restrict__ psum)
{
  __shared__ ushort_t sW1[256 * 128];   // [n1][swizzled k=e]   65536 B
  __shared__ ushort_t sW2[128 * 256];   // [n2][swizzled k=n1]  65536 B
  __shared__ ushort_t sW3[64 * 128];    // [n3][swizzled k=n2]  16384 B
  __shared__ float sC[520];             // c[256]|b2[128]|b3[64]|W4[64]|b4
  __shared__ float sT[512];             // cvec partials

  const int tid = threadIdx.x;

  // ---- one-time staging: fp32 global -> bf16 LDS, transposed + block-swizzled ----
  for (int idx = tid; idx < 32768; idx += 512) {
    int n = idx & 255, k = idx >> 8;              // n1, e (k<128)
    int bp = ((k >> 3) + 2 * n) & 15;
    sW1[n * 128 + bp * 8 + (k & 7)] = f2bf(W1[(256 + k) * 256 + n]);
  }
  for (int idx = tid; idx < 32768; idx += 512) {
    int n = idx & 127, k = idx >> 7;              // n2, n1 (k<256)
    int bp = ((k >> 3) + 2 * n) & 31;
    sW2[n * 256 + bp * 8 + (k & 7)] = f2bf(W2[k * 128 + n]);
  }
  for (int idx = tid; idx < 8192; idx += 512) {
    int n = idx & 63, k = idx >> 6;               // n3, n2 (k<128)
    int bp = ((k >> 3) + 2 * n) & 15;
    sW3[n * 128 + bp * 8 + (k & 7)] = f2bf(W3[k * 64 + n]);
  }
  if (tid >= 256 && tid < 384) sC[tid] = b2[tid - 256];
  else if (tid >= 384 && tid < 448) sC[tid] = b3[tid - 384];
  else if (tid >= 448) sC[tid] = W4[tid - 448];
  if (tid == 0) sC[512] = b4[0];
  { // inlined cvec: c[j] = b1[j] + mu_in . W1[0:128,j] + mu_not . W1[128:256,j]
    const int j = tid & 255, h = tid >> 8;        // h = 0..1
    float c = h ? 0.f : b1[j];
    #pragma unroll 8
    for (int e = 64 * h; e < 64 * h + 64; ++e) {
      c += mu_in[e]  * W1[e * 256 + j];
      c += mu_not[e] * W1[(128 + e) * 256 + j];
    }
    sT[tid] = c;
  }
  __syncthreads();
  if (tid < 256) sC[tid] = sT[tid] + sT[tid + 256];
  __syncthreads();   // last block-wide barrier

  const int wave = tid >> 6, lane = tid & 63;
  const int lr = lane & 15, lg = lane >> 4;
  const int wid = blockIdx.x * 8 + wave;          // 0..2047
  const bool b0 = lg & 1, b1f = lg & 2;           // butterfly selectors
  const int sw = lg + 2 * lr;                     // swizzle read term

  const ushort_t* w1p = sW1 + lr * 128;           // + mt*2048 + ((4kt+sw)&15)*8
  const ushort_t* w2p = sW2 + lr * 256;           // + mt*4096 + ((4kt+sw)&31)*8
  const ushort_t* w3p = sW3 + lr * 128;           // + mt*2048 + ((4kt+sw)&15)*8

  float es = 0.f;
  bf16x8 B1a[4], B1b[4];

  // descending iteration: it = it_hi .. 0, r0 = wid*32 + it*65536
  const int it_hi = (NN - 1 - wid * 32) / 65536;  // 6 or 7; all rows covered exactly

  // preload + convert first (highest) 32-row group
  {
    const int r0 = wid * 32 + it_hi * 65536;
    const float4* pa = (const float4*)(enc + (size_t)(r0 + lr) * 128);
    const float4* pb = (const float4*)(enc + (size_t)(r0 + 16 + lr) * 128);
    #pragma unroll
    for (int kt = 0; kt < 4; ++kt) {
      float4 f0 = pa[kt * 8 + lg * 2], f1 = pa[kt * 8 + lg * 2 + 1];
      float4 g0 = pb[kt * 8 + lg * 2], g1 = pb[kt * 8 + lg * 2 + 1];
      bf16x8 a, b;
      a[0] = (__bf16)f0.x; a[1] = (__bf16)f0.y; a[2] = (__bf16)f0.z; a[3] = (__bf16)f0.w;
      a[4] = (__bf16)f1.x; a[5] = (__bf16)f1.y; a[6] = (__bf16)f1.z; a[7] = (__bf16)f1.w;
      b[0] = (__bf16)g0.x; b[1] = (__bf16)g0.y; b[2] = (__bf16)g0.z; b[3] = (__bf16)g0.w;
      b[4] = (__bf16)g1.x; b[5] = (__bf16)g1.y; b[6] = (__bf16)g1.z; b[7] = (__bf16)g1.w;
      B1a[kt] = a; B1b[kt] = b;
    }
  }

  for (int it = it_hi; it >= 0; --it) {
    const int r0 = wid * 32 + it * 65536;
    // ---- L1: mt-pairs; each weight read feeds groups a AND b ----
    bf16x8 B2a[8], B2b[8];
    #pragma unroll
    for (int p = 0; p < 8; ++p) {
      f32x4 aA0 = (f32x4){0.f,0.f,0.f,0.f}, aA1 = (f32x4){0.f,0.f,0.f,0.f};
      f32x4 aB0 = (f32x4){0.f,0.f,0.f,0.f}, aB1 = (f32x4){0.f,0.f,0.f,0.f};
      PRIO(1);
      #pragma unroll
      for (int kt = 0; kt < 4; ++kt) {
        bf16x8 wA = *(const bf16x8*)(w1p + (2 * p) * 2048 + (((4 * kt + sw) & 15) << 3));
        bf16x8 wB = *(const bf16x8*)(w1p + (2 * p + 1) * 2048 + (((4 * kt + sw) & 15) << 3));
        aA0 = __builtin_amdgcn_mfma_f32_16x16x32_bf16(wA, B1a[kt], aA0, 0, 0, 0);
        aA1 = __builtin_amdgcn_mfma_f32_16x16x32_bf16(wB, B1a[kt], aA1, 0, 0, 0);
        aB0 = __builtin_amdgcn_mfma_f32_16x16x32_bf16(wA, B1b[kt], aB0, 0, 0, 0);
        aB1 = __builtin_amdgcn_mfma_f32_16x16x32_bf16(wB, B1b[kt], aB1, 0, 0, 0);
      }
      PRIO(0);
      float4 cb0 = *(const float4*)(sC + 16 * (2 * p) + 4 * lg);
      float4 cb1 = *(const float4*)(sC + 16 * (2 * p + 1) + 4 * lg);
      {
        unsigned q0 = pk2(lrelu(aA0[0] + cb0.x), lrelu(aA0[1] + cb0.y));
        unsigned q1 = pk2(lrelu(aA0[2] + cb0.z), lrelu(aA0[3] + cb0.w));
        unsigned q2 = pk2(lrelu(aA1[0] + cb1.x), lrelu(aA1[1] + cb1.y));
        unsigned q3 = pk2(lrelu(aA1[2] + cb1.z), lrelu(aA1[3] + cb1.w));
        unsigned w0, w1, w2, w3;
        bfly4(q0, q1, q2, q3, b0, b1f, w0, w1, w2, w3);
        B2a[p] = mk8(w0, w1, w2, w3);
      }
      {
        unsigned q0 = pk2(lrelu(aB0[0] + cb0.x), lrelu(aB0[1] + cb0.y));
        unsigned q1 = pk2(lrelu(aB0[2] + cb0.z), lrelu(aB0[3] + cb0.w));
        unsigned q2 = pk2(lrelu(aB1[0] + cb1.x), lrelu(aB1[1] + cb1.y));
        unsigned q3 = pk2(lrelu(aB1[2] + cb1.z), lrelu(aB1[3] + cb1.w));
        unsigned w0, w1, w2, w3;
        bfly4(q0, q1, q2, q3, b0, b1f, w0, w1, w2, w3);
        B2b[p] = mk8(w0, w1, w2, w3);
      }
    }
    SBAR();   // phase fence: keep L2's ds_reads from hoisting into L1
    // ---- L2: mt-pairs -> B3a/B3b ----
    bf16x8 B3a[4], B3b[4];
    #pragma unroll
    for (int p = 0; p < 4; ++p) {
      f32x4 aA0 = (f32x4){0.f,0.f,0.f,0.f}, aA1 = (f32x4){0.f,0.f,0.f,0.f};
      f32x4 aB0 = (f32x4){0.f,0.f,0.f,0.f}, aB1 = (f32x4){0.f,0.f,0.f,0.f};
      PRIO(1);
      #pragma unroll
      for (int kt = 0; kt < 8; ++kt) {
        bf16x8 wA = *(const bf16x8*)(w2p + (2 * p) * 4096 + (((4 * kt + sw) & 31) << 3));
        bf16x8 wB = *(const bf16x8*)(w2p + (2 * p + 1) * 4096 + (((4 * kt + sw) & 31) << 3));
        aA0 = __builtin_amdgcn_mfma_f32_16x16x32_bf16(wA, B2a[kt], aA0, 0, 0, 0);
        aA1 = __builtin_amdgcn_mfma_f32_16x16x32_bf16(wB, B2a[kt], aA1, 0, 0, 0);
        aB0 = __builtin_amdgcn_mfma_f32_16x16x32_bf16(wA, B2b[kt], aB0, 0, 0, 0);
        aB1 = __builtin_amdgcn_mfma_f32_16x16x32_bf16(wB, B2b[kt], aB1, 0, 0, 0);
      }
      PRIO(0);
      float4 cb0 = *(const float4*)(sC + 256 + 16 * (2 * p) + 4 * lg);
      float4 cb1 = *(const float4*)(sC + 256 + 16 * (2 * p + 1) + 4 * lg);
      {
        unsigned q0 = pk2(lrelu(aA0[0] + cb0.x), lrelu(aA0[1] + cb0.y));
        unsigned q1 = pk2(lrelu(aA0[2] + cb0.z), lrelu(aA0[3] + cb0.w));
        unsigned q2 = pk2(lrelu(aA1[0] + cb1.x), lrelu(aA1[1] + cb1.y));
        unsigned q3 = pk2(lrelu(aA1[2] + cb1.z), lrelu(aA1[3] + cb1.w));
        unsigned w0, w1, w2, w3;
        bfly4(q0, q1, q2, q3, b0, b1f, w0, w1, w2, w3);
        B3a[p] = mk8(w0, w1, w2, w3);
      }
      {
        unsigned q0 = pk2(lrelu(aB0[0] + cb0.x), lrelu(aB0[1] + cb0.y));
        unsigned q1 = pk2(lrelu(aB0[2] + cb0.z), lrelu(aB0[3] + cb0.w));
        unsigned q2 = pk2(lrelu(aB1[0] + cb1.x), lrelu(aB1[1] + cb1.y));
        unsigned q3 = pk2(lrelu(aB1[2] + cb1.z), lrelu(aB1[3] + cb1.w));
        unsigned w0, w1, w2, w3;
        bfly4(q0, q1, q2, q3, b0, b1f, w0, w1, w2, w3);
        B3b[p] = mk8(w0, w1, w2, w3);
      }
    }
    SBAR();   // phase fence
    // ---- prefetch next (lower) 32-row group; consumed at loop bottom ----
    const int rn = (it > 0) ? (r0 - 65536) : r0;  // it==0: dummy reload
    float4 tA[8], tB[8];
    {
      const float4* pa = (const float4*)(enc + (size_t)(rn + lr) * 128);
      const float4* pb = (const float4*)(enc + (size_t)(rn + 16 + lr) * 128);
      #pragma unroll
      for (int kt = 0; kt < 4; ++kt) {
        tA[2 * kt]     = pa[kt * 8 + lg * 2];
        tA[2 * kt + 1] = pa[kt * 8 + lg * 2 + 1];
        tB[2 * kt]     = pb[kt * 8 + lg * 2];
        tB[2 * kt + 1] = pb[kt * 8 + lg * 2 + 1];
      }
    }
    SBAR();   // pin the load-issue position (do not sink into L3)
    // ---- L3 (mt-pairs) + L4 epilogue folded into W4 dot, both groups ----
    float da = 0.f, db = 0.f;
    #pragma unroll
    for (int p = 0; p < 2; ++p) {
      f32x4 aA0 = (f32x4){0.f,0.f,0.f,0.f}, aA1 = (f32x4){0.f,0.f,0.f,0.f};
      f32x4 aB0 = (f32x4){0.f,0.f,0.f,0.f}, aB1 = (f32x4){0.f,0.f,0.f,0.f};
      PRIO(1);
      #pragma unroll
      for (int kt = 0; kt < 4; ++kt) {
        bf16x8 wA = *(const bf16x8*)(w3p + (2 * p) * 2048 + (((4 * kt + sw) & 15) << 3));
        bf16x8 wB = *(const bf16x8*)(w3p + (2 * p + 1) * 2048 + (((4 * kt + sw) & 15) << 3));
        aA0 = __builtin_amdgcn_mfma_f32_16x16x32_bf16(wA, B3a[kt], aA0, 0, 0, 0);
        aA1 = __builtin_amdgcn_mfma_f32_16x16x32_bf16(wB, B3a[kt], aA1, 0, 0, 0);
        aB0 = __builtin_amdgcn_mfma_f32_16x16x32_bf16(wA, B3b[kt], aB0, 0, 0, 0);
        aB1 = __builtin_amdgcn_mfma_f32_16x16x32_bf16(wB, B3b[kt], aB1, 0, 0, 0);
      }
      PRIO(0);
      float4 cb0  = *(const float4*)(sC + 384 + 16 * (2 * p) + 4 * lg);
      float4 cb1  = *(const float4*)(sC + 384 + 16 * (2 * p + 1) + 4 * lg);
      float4 w4v0 = *(const float4*)(sC + 448 + 16 * (2 * p) + 4 * lg);
      float4 w4v1 = *(const float4*)(sC + 448 + 16 * (2 * p + 1) + 4 * lg);
      da += lrelu(aA0[0] + cb0.x) * w4v0.x + lrelu(aA0[1] + cb0.y) * w4v0.y
          + lrelu(aA0[2] + cb0.z) * w4v0.z + lrelu(aA0[3] + cb0.w) * w4v0.w;
      da += lrelu(aA1[0] + cb1.x) * w4v1.x + lrelu(aA1[1] + cb1.y) * w4v1.y
          + lrelu(aA1[2] + cb1.z) * w4v1.z + lrelu(aA1[3] + cb1.w) * w4v1.w;
      db += lrelu(aB0[0] + cb0.x) * w4v0.x + lrelu(aB0[1] + cb0.y) * w4v0.y
          + lrelu(aB0[2] + cb0.z) * w4v0.z + lrelu(aB0[3] + cb0.w) * w4v0.w;
      db += lrelu(aB1[0] + cb1.x) * w4v1.x + lrelu(aB1[1] + cb1.y) * w4v1.y
          + lrelu(aB1[2] + cb1.z) * w4v1.z + lrelu(aB1[3] + cb1.w) * w4v1.w;
    }
    da += __shfl_xor(da, 16, 64); da += __shfl_xor(da, 32, 64);
    db += __shfl_xor(db, 16, 64); db += __shfl_xor(db, 32, 64);
    float eva = expf(da + sC[512]), evb = expf(db + sC[512]);
    if (lg == 0) { eL[r0 + lr] = eva; eL[r0 + 16 + lr] = evb; }
    es += eva + evb;                 // 4x duplicated across lg, scaled at the end
    // ---- convert prefetched rows -> B1a/B1b for next iteration ----
    #pragma unroll
    for (int kt = 0; kt < 4; ++kt) {
      float4 f0 = tA[2 * kt], f1 = tA[2 * kt + 1];
      float4 g0 = tB[2 * kt], g1 = tB[2 * kt + 1];
      bf16x8 a, b;
      a[0] = (__bf16)f0.x; a[1] = (__bf16)f0.y; a[2] = (__bf16)f0.z; a[3] = (__bf16)f0.w;
      a[4] = (__bf16)f1.x; a[5] = (__bf16)f1.y; a[6] = (__bf16)f1.z; a[7] = (__bf16)f1.w;
      b[0] = (__bf16)g0.x; b[1] = (__bf16)g0.y; b[2] = (__bf16)g0.z; b[3] = (__bf16)g0.w;
      b[4] = (__bf16)g1.x; b[5] = (__bf16)g1.y; b[6] = (__bf16)g1.z; b[7] = (__bf16)g1.w;
      B1a[kt] = a; B1b[kt] = b;
    }
  }
  // wave-wide partial softmax denominator (deterministic: one slot per wave)
  #pragma unroll
  for (int off = 1; off < 64; off <<= 1) es += __shfl_xor(es, off, 64);
  if (lane == 0) psum[wid] = 0.25f * es;
}

// ---------------- k_norm: per-block redundant psum reduce (identical order ->
// identical scal, deterministic) + normalize. Replaces separate k_finalsum. --------------
__global__ __launch_bounds__(256) void k_norm(const float* __restrict__ eL,
                                              const float* __restrict__ psum,
                                              float* __restrict__ out)
{
  __shared__ float sr[4];
  const int tid = threadIdx.x;
  float s = 0.f;
  #pragma unroll
  for (int k = 0; k < 8; ++k) s += psum[tid + k * 256];
  #pragma unroll
  for (int off = 1; off < 64; off <<= 1) s += __shfl_xor(s, off, 64);
  if ((tid & 63) == 0) sr[tid >> 6] = s;
  __syncthreads();
  const float inv = 1.f / (sr[0] + sr[1] + sr[2] + sr[3]);
  const int i = blockIdx.x * 256 + tid;
  if (i < NN / 4) {
    float4 v = ((const float4*)eL)[i];
    float4 o = {v.x * inv, v.y * inv, v.z * inv, v.w * inv};
    ((float4*)out)[i] = o;
  }
}

extern "C" void kernel_launch(void* const* d_in, const int* in_sizes, int n_in,
                              void* d_out, int out_size, void* d_ws, size_t ws_size,
                              hipStream_t stream) {
  const float* enc = (const float*)d_in[0];
  const int*   cs  = (const int*)d_in[1];
  const float* W1  = (const float*)d_in[2];
  const float* b1  = (const float*)d_in[3];
  const float* W2  = (const float*)d_in[4];
  const float* b2  = (const float*)d_in[5];
  const float* W3  = (const float*)d_in[6];
  const float* b3  = (const float*)d_in[7];
  const float* W4  = (const float*)d_in[8];
  const float* b4  = (const float*)d_in[9];
  float* out = (float*)d_out;

  char* ws = (char*)d_ws;
  float* mu_in  = (float*)(ws + 0);        // 512 B
  float* mu_not = (float*)(ws + 512);      // 512 B
  float* psum   = (float*)(ws + 2048);     // 2048 floats = 8 KB
  float* red2   = (float*)(ws + 16384);    // 64*256*4 = 64 KB
  float* eLbuf  = (float*)(ws + 131072);   // 2 MB (exp(logit) per row)
  // colmax partials alias the eL region: live only BEFORE k_mlp writes eL.
  float* partials = (float*)(ws + 131072); // 2000*256*4 = 2,048,000 B

  k_colmax<<<dim3(NBLK_CM), dim3(256), 0, stream>>>(enc, cs, partials);
  k_red1<<<dim3(64), dim3(256), 0, stream>>>(partials, red2);
  k_red2<<<dim3(1), dim3(1024), 0, stream>>>(red2, mu_in, mu_not);
  k_mlp<<<dim3(256), dim3(512), 0, stream>>>(enc, W1, b1, W2, b2, W3, b3, W4, b4,
                                             mu_in, mu_not, eLbuf, psum);
  k_norm<<<dim3(489), dim3(256), 0, stream>>>(eLbuf, psum, out);
}

// Round 12
// 167.098 us; speedup vs baseline: 2.0137x; 1.0232x over previous
//
#include <hip/hip_runtime.h>
#include <hip/hip_bf16.h>

#define NN 500000
#define NBLK_CM 2000   // colmax blocks: 2000 * 250 rows = 500,000 exact
// feats = [mu_in(128) | mu_not(128) | enc(128)]; H1=256, H2=128, H3=64

typedef unsigned short ushort_t;
typedef __attribute__((ext_vector_type(8))) __bf16 bf16x8;
typedef __attribute__((ext_vector_type(2))) __bf16 bf16x2;
typedef __attribute__((ext_vector_type(4))) float f32x4;
typedef __attribute__((ext_vector_type(4))) unsigned uint4v;

__device__ inline ushort_t f2bf(float f) {
  unsigned u = __builtin_bit_cast(unsigned, f);
  return (ushort_t)((u + 0x7FFFu + ((u >> 16) & 1u)) >> 16);
}
__device__ inline float lrelu(float v) { return fmaxf(v, 0.f) + 0.01f * fminf(v, 0.f); }
__device__ inline unsigned pk2(float lo, float hi) {
  bf16x2 v; v[0] = (__bf16)lo; v[1] = (__bf16)hi;
  return __builtin_bit_cast(unsigned, v);
}
__device__ inline bf16x8 mk8(unsigned w0, unsigned w1, unsigned w2, unsigned w3) {
  uint4v u; u.x = w0; u.y = w1; u.z = w2; u.w = w3;
  return __builtin_bit_cast(bf16x8, u);
}
#define SBAR() __builtin_amdgcn_sched_barrier(0)
#define PRIO(n) __builtin_amdgcn_s_setprio(n)

// ---------------- K_colmax: masked per-column max -> per-block partials (NO atomics) ----
__global__ __launch_bounds__(256) void k_colmax(
    const float* __restrict__ enc, const int* __restrict__ cs,
    float* __restrict__ partials)            // [NBLK_CM][256]: in(128)|not(128)
{
  __shared__ float4 s_in[256], s_not[256];
  const int tid = threadIdx.x;
  const int c4 = tid & 31;    // float4-column 0..31
  const int rs = tid >> 5;    // row slice 0..7
  const long base = (long)blockIdx.x * 250;
  float4 mi = {0.f, 0.f, 0.f, 0.f}, mn = {0.f, 0.f, 0.f, 0.f};
  const float4* e4 = (const float4*)enc;
  #pragma unroll 4
  for (int it = 0; it < 32; ++it) {        // 8 slices x 32 = 256 rows >= 250 (guarded)
    long r = base + rs + 8L * it;
    if (r < base + 250 && r < NN) {
      float4 v = e4[r * 32 + c4];
      bool ins = cs[r] > 0;
      mi.x = fmaxf(mi.x, ins ? v.x : 0.f); mi.y = fmaxf(mi.y, ins ? v.y : 0.f);
      mi.z = fmaxf(mi.z, ins ? v.z : 0.f); mi.w = fmaxf(mi.w, ins ? v.w : 0.f);
      mn.x = fmaxf(mn.x, ins ? 0.f : v.x); mn.y = fmaxf(mn.y, ins ? 0.f : v.y);
      mn.z = fmaxf(mn.z, ins ? 0.f : v.z); mn.w = fmaxf(mn.w, ins ? 0.f : v.w);
    }
  }
  s_in[tid] = mi; s_not[tid] = mn;
  __syncthreads();
  if (tid < 32) {
    for (int j = 1; j < 8; ++j) {
      float4 a = s_in[j * 32 + tid], b = s_not[j * 32 + tid];
      mi.x = fmaxf(mi.x, a.x); mi.y = fmaxf(mi.y, a.y);
      mi.z = fmaxf(mi.z, a.z); mi.w = fmaxf(mi.w, a.w);
      mn.x = fmaxf(mn.x, b.x); mn.y = fmaxf(mn.y, b.y);
      mn.z = fmaxf(mn.z, b.z); mn.w = fmaxf(mn.w, b.w);
    }
    float* po = partials + (size_t)blockIdx.x * 256;
    ((float4*)po)[tid] = mi;           // cols 4t..4t+3 of mu_in partial
    ((float4*)(po + 128))[tid] = mn;   // mu_not partial
  }
}

// ---------------- K_red1: 64 blocks fold 2000 partial rows -> red2[64][256] ------------
__global__ __launch_bounds__(256) void k_red1(
    const float* __restrict__ partials, float* __restrict__ red2)
{
  const int tid = threadIdx.x, b = blockIdx.x;
  float m = 0.f;               // identity: masked max >= 0
  #pragma unroll 8
  for (int row = b; row < NBLK_CM; row += 64)
    m = fmaxf(m, partials[(size_t)row * 256 + tid]);
  red2[b * 256 + tid] = m;
}

// ---------------- K_red2: 1 block folds red2[64][256] -> mu_in/mu_not ------------------
__global__ __launch_bounds__(1024) void k_red2(
    const float* __restrict__ red2,
    float* __restrict__ mu_in, float* __restrict__ mu_not)
{
  __shared__ float sT[1024];
  const int tid = threadIdx.x;
  const int col = tid & 255, sl = tid >> 8;     // 4 slices x 16 rows
  float m = 0.f;
  #pragma unroll
  for (int j = 0; j < 16; ++j)
    m = fmaxf(m, red2[(sl * 16 + j) * 256 + col]);
  sT[tid] = m;
  __syncthreads();
  if (tid < 256) {
    m = fmaxf(fmaxf(sT[tid], sT[tid + 256]), fmaxf(sT[tid + 512], sT[tid + 768]));
    if (tid < 128) mu_in[tid] = m;
    else           mu_not[tid - 128] = m;
  }
}

// ---------------- K_mlp: persistent, weights LDS-resident, barrier-free loop -------------
// Round-12: ZERO-SHUFFLE layer handoff. The GEMM k-contraction is order-free, so W2/W3
// are staged with a permuted k-labeling pi(kt,i,g) = 16*(2kt+(i>>2)) + 4g + (i&3) chosen
// so layer n's D-output register layout IS layer n+1's B-operand layout:
//   B2[p] = mk8(q0,q1,q2,q3) of the packed epilogue words, verbatim.
// This deletes all bfly4 butterflies (~96 DS-pipe shuffle ops + ~300 VALU / wave-iter,
// ~35% of the bottleneck DS pipe). MFMA k-summation order changes -> absmax shifts
// ~1e-9 (<< threshold). Everything else identical to round 11.
__global__ __launch_bounds__(512)
__attribute__((amdgpu_waves_per_eu(2, 2)))
void k_mlp(
    const float* __restrict__ enc,
    const float* __restrict__ W1, const float* __restrict__ b1,
    const float* __restrict__ W2, const float* __restrict__ b2,
    const float* __restrict__ W3, const float* __restrict__ b3,
    const float* __restrict__ W4, const float* __restrict__ b4,
    const float* __restrict__ mu_in, const float* __restrict__ mu_not,
    float* __restrict__ eL, float* __restrict__ psum)
{
  __shared__ ushort_t sW1[256 * 128];   // [n1][swizzled k=e]        65536 B
  __shared__ ushort_t sW2[128 * 256];   // [n2][swizzled k=pi(n1)]   65536 B
  __shared__ ushort_t sW3[64 * 128];    // [n3][swizzled k=pi(n2)]   16384 B
  __shared__ float sC[520];             // c[256]|b2[128]|b3[64]|W4[64]|b4
  __shared__ float sT[512];             // cvec partials

  const int tid = threadIdx.x;

  // ---- one-time staging: fp32 global -> bf16 LDS, transposed + block-swizzled ----
  for (int idx = tid; idx < 32768; idx += 512) {
    int n = idx & 255, k = idx >> 8;              // n1, e (k<128) -- L1 B is enc: no pi
    int bp = ((k >> 3) + 2 * n) & 15;
    sW1[n * 128 + bp * 8 + (k & 7)] = f2bf(W1[(256 + k) * 256 + n]);
  }
  for (int idx = tid; idx < 32768; idx += 512) {
    int n = idx & 127, k = idx >> 7;              // n2, linear k-slot (k<256)
    int kt = k >> 5, g = (k >> 3) & 3, i = k & 7;
    int n1 = 16 * (2 * kt + (i >> 2)) + 4 * g + (i & 3);   // pi: h1-index for this slot
    int bp = ((k >> 3) + 2 * n) & 31;
    sW2[n * 256 + bp * 8 + (k & 7)] = f2bf(W2[n1 * 128 + n]);
  }
  for (int idx = tid; idx < 8192; idx += 512) {
    int n = idx & 63, k = idx >> 6;               // n3, linear k-slot (k<128)
    int kt = k >> 5, g = (k >> 3) & 3, i = k & 7;
    int n2 = 16 * (2 * kt + (i >> 2)) + 4 * g + (i & 3);   // pi: h2-index for this slot
    int bp = ((k >> 3) + 2 * n) & 15;
    sW3[n * 128 + bp * 8 + (k & 7)] = f2bf(W3[n2 * 64 + n]);
  }
  if (tid >= 256 && tid < 384) sC[tid] = b2[tid - 256];
  else if (tid >= 384 && tid < 448) sC[tid] = b3[tid - 384];
  else if (tid >= 448) sC[tid] = W4[tid - 448];
  if (tid == 0) sC[512] = b4[0];
  { // inlined cvec: c[j] = b1[j] + mu_in . W1[0:128,j] + mu_not . W1[128:256,j]
    const int j = tid & 255, h = tid >> 8;        // h = 0..1
    float c = h ? 0.f : b1[j];
    #pragma unroll 8
    for (int e = 64 * h; e < 64 * h + 64; ++e) {
      c += mu_in[e]  * W1[e * 256 + j];
      c += mu_not[e] * W1[(128 + e) * 256 + j];
    }
    sT[tid] = c;
  }
  __syncthreads();
  if (tid < 256) sC[tid] = sT[tid] + sT[tid + 256];
  __syncthreads();   // last block-wide barrier

  const int wave = tid >> 6, lane = tid & 63;
  const int lr = lane & 15, lg = lane >> 4;
  const int wid = blockIdx.x * 8 + wave;          // 0..2047
  const int sw = lg + 2 * lr;                     // swizzle read term

  const ushort_t* w1p = sW1 + lr * 128;           // + mt*2048 + ((4kt+sw)&15)*8
  const ushort_t* w2p = sW2 + lr * 256;           // + mt*4096 + ((4kt+sw)&31)*8
  const ushort_t* w3p = sW3 + lr * 128;           // + mt*2048 + ((4kt+sw)&15)*8

  float es = 0.f;
  bf16x8 B1a[4], B1b[4];

  // descending iteration: it = it_hi .. 0, r0 = wid*32 + it*65536
  const int it_hi = (NN - 1 - wid * 32) / 65536;  // 6 or 7; all rows covered exactly

  // preload + convert first (highest) 32-row group
  {
    const int r0 = wid * 32 + it_hi * 65536;
    const float4* pa = (const float4*)(enc + (size_t)(r0 + lr) * 128);
    const float4* pb = (const float4*)(enc + (size_t)(r0 + 16 + lr) * 128);
    #pragma unroll
    for (int kt = 0; kt < 4; ++kt) {
      float4 f0 = pa[kt * 8 + lg * 2], f1 = pa[kt * 8 + lg * 2 + 1];
      float4 g0 = pb[kt * 8 + lg * 2], g1 = pb[kt * 8 + lg * 2 + 1];
      bf16x8 a, b;
      a[0] = (__bf16)f0.x; a[1] = (__bf16)f0.y; a[2] = (__bf16)f0.z; a[3] = (__bf16)f0.w;
      a[4] = (__bf16)f1.x; a[5] = (__bf16)f1.y; a[6] = (__bf16)f1.z; a[7] = (__bf16)f1.w;
      b[0] = (__bf16)g0.x; b[1] = (__bf16)g0.y; b[2] = (__bf16)g0.z; b[3] = (__bf16)g0.w;
      b[4] = (__bf16)g1.x; b[5] = (__bf16)g1.y; b[6] = (__bf16)g1.z; b[7] = (__bf16)g1.w;
      B1a[kt] = a; B1b[kt] = b;
    }
  }

  for (int it = it_hi; it >= 0; --it) {
    const int r0 = wid * 32 + it * 65536;
    // ---- L1: mt-pairs; epilogue packs feed B2 DIRECTLY (pi-relabeled weights) ----
    bf16x8 B2a[8], B2b[8];
    #pragma unroll
    for (int p = 0; p < 8; ++p) {
      f32x4 aA0 = (f32x4){0.f,0.f,0.f,0.f}, aA1 = (f32x4){0.f,0.f,0.f,0.f};
      f32x4 aB0 = (f32x4){0.f,0.f,0.f,0.f}, aB1 = (f32x4){0.f,0.f,0.f,0.f};
      PRIO(1);
      #pragma unroll
      for (int kt = 0; kt < 4; ++kt) {
        bf16x8 wA = *(const bf16x8*)(w1p + (2 * p) * 2048 + (((4 * kt + sw) & 15) << 3));
        bf16x8 wB = *(const bf16x8*)(w1p + (2 * p + 1) * 2048 + (((4 * kt + sw) & 15) << 3));
        aA0 = __builtin_amdgcn_mfma_f32_16x16x32_bf16(wA, B1a[kt], aA0, 0, 0, 0);
        aA1 = __builtin_amdgcn_mfma_f32_16x16x32_bf16(wB, B1a[kt], aA1, 0, 0, 0);
        aB0 = __builtin_amdgcn_mfma_f32_16x16x32_bf16(wA, B1b[kt], aB0, 0, 0, 0);
        aB1 = __builtin_amdgcn_mfma_f32_16x16x32_bf16(wB, B1b[kt], aB1, 0, 0, 0);
      }
      PRIO(0);
      float4 cb0 = *(const float4*)(sC + 16 * (2 * p) + 4 * lg);
      float4 cb1 = *(const float4*)(sC + 16 * (2 * p + 1) + 4 * lg);
      B2a[p] = mk8(pk2(lrelu(aA0[0] + cb0.x), lrelu(aA0[1] + cb0.y)),
                   pk2(lrelu(aA0[2] + cb0.z), lrelu(aA0[3] + cb0.w)),
                   pk2(lrelu(aA1[0] + cb1.x), lrelu(aA1[1] + cb1.y)),
                   pk2(lrelu(aA1[2] + cb1.z), lrelu(aA1[3] + cb1.w)));
      B2b[p] = mk8(pk2(lrelu(aB0[0] + cb0.x), lrelu(aB0[1] + cb0.y)),
                   pk2(lrelu(aB0[2] + cb0.z), lrelu(aB0[3] + cb0.w)),
                   pk2(lrelu(aB1[0] + cb1.x), lrelu(aB1[1] + cb1.y)),
                   pk2(lrelu(aB1[2] + cb1.z), lrelu(aB1[3] + cb1.w)));
    }
    SBAR();   // phase fence: keep L2's ds_reads from hoisting into L1
    // ---- L2: mt-pairs -> B3a/B3b (direct pack) ----
    bf16x8 B3a[4], B3b[4];
    #pragma unroll
    for (int p = 0; p < 4; ++p) {
      f32x4 aA0 = (f32x4){0.f,0.f,0.f,0.f}, aA1 = (f32x4){0.f,0.f,0.f,0.f};
      f32x4 aB0 = (f32x4){0.f,0.f,0.f,0.f}, aB1 = (f32x4){0.f,0.f,0.f,0.f};
      PRIO(1);
      #pragma unroll
      for (int kt = 0; kt < 8; ++kt) {
        bf16x8 wA = *(const bf16x8*)(w2p + (2 * p) * 4096 + (((4 * kt + sw) & 31) << 3));
        bf16x8 wB = *(const bf16x8*)(w2p + (2 * p + 1) * 4096 + (((4 * kt + sw) & 31) << 3));
        aA0 = __builtin_amdgcn_mfma_f32_16x16x32_bf16(wA, B2a[kt], aA0, 0, 0, 0);
        aA1 = __builtin_amdgcn_mfma_f32_16x16x32_bf16(wB, B2a[kt], aA1, 0, 0, 0);
        aB0 = __builtin_amdgcn_mfma_f32_16x16x32_bf16(wA, B2b[kt], aB0, 0, 0, 0);
        aB1 = __builtin_amdgcn_mfma_f32_16x16x32_bf16(wB, B2b[kt], aB1, 0, 0, 0);
      }
      PRIO(0);
      float4 cb0 = *(const float4*)(sC + 256 + 16 * (2 * p) + 4 * lg);
      float4 cb1 = *(const float4*)(sC + 256 + 16 * (2 * p + 1) + 4 * lg);
      B3a[p] = mk8(pk2(lrelu(aA0[0] + cb0.x), lrelu(aA0[1] + cb0.y)),
                   pk2(lrelu(aA0[2] + cb0.z), lrelu(aA0[3] + cb0.w)),
                   pk2(lrelu(aA1[0] + cb1.x), lrelu(aA1[1] + cb1.y)),
                   pk2(lrelu(aA1[2] + cb1.z), lrelu(aA1[3] + cb1.w)));
      B3b[p] = mk8(pk2(lrelu(aB0[0] + cb0.x), lrelu(aB0[1] + cb0.y)),
                   pk2(lrelu(aB0[2] + cb0.z), lrelu(aB0[3] + cb0.w)),
                   pk2(lrelu(aB1[0] + cb1.x), lrelu(aB1[1] + cb1.y)),
                   pk2(lrelu(aB1[2] + cb1.z), lrelu(aB1[3] + cb1.w)));
    }
    SBAR();   // phase fence
    // ---- prefetch next (lower) 32-row group; consumed at loop bottom ----
    const int rn = (it > 0) ? (r0 - 65536) : r0;  // it==0: dummy reload
    float4 tA[8], tB[8];
    {
      const float4* pa = (const float4*)(enc + (size_t)(rn + lr) * 128);
      const float4* pb = (const float4*)(enc + (size_t)(rn + 16 + lr) * 128);
      #pragma unroll
      for (int kt = 0; kt < 4; ++kt) {
        tA[2 * kt]     = pa[kt * 8 + lg * 2];
        tA[2 * kt + 1] = pa[kt * 8 + lg * 2 + 1];
        tB[2 * kt]     = pb[kt * 8 + lg * 2];
        tB[2 * kt + 1] = pb[kt * 8 + lg * 2 + 1];
      }
    }
    SBAR();   // pin the load-issue position (do not sink into L3)
    // ---- L3 (mt-pairs) + L4 epilogue folded into W4 dot, both groups ----
    float da = 0.f, db = 0.f;
    #pragma unroll
    for (int p = 0; p < 2; ++p) {
      f32x4 aA0 = (f32x4){0.f,0.f,0.f,0.f}, aA1 = (f32x4){0.f,0.f,0.f,0.f};
      f32x4 aB0 = (f32x4){0.f,0.f,0.f,0.f}, aB1 = (f32x4){0.f,0.f,0.f,0.f};
      PRIO(1);
      #pragma unroll
      for (int kt = 0; kt < 4; ++kt) {
        bf16x8 wA = *(const bf16x8*)(w3p + (2 * p) * 2048 + (((4 * kt + sw) & 15) << 3));
        bf16x8 wB = *(const bf16x8*)(w3p + (2 * p + 1) * 2048 + (((4 * kt + sw) & 15) << 3));
        aA0 = __builtin_amdgcn_mfma_f32_16x16x32_bf16(wA, B3a[kt], aA0, 0, 0, 0);
        aA1 = __builtin_amdgcn_mfma_f32_16x16x32_bf16(wB, B3a[kt], aA1, 0, 0, 0);
        aB0 = __builtin_amdgcn_mfma_f32_16x16x32_bf16(wA, B3b[kt], aB0, 0, 0, 0);
        aB1 = __builtin_amdgcn_mfma_f32_16x16x32_bf16(wB, B3b[kt], aB1, 0, 0, 0);
      }
      PRIO(0);
      float4 cb0  = *(const float4*)(sC + 384 + 16 * (2 * p) + 4 * lg);
      float4 cb1  = *(const float4*)(sC + 384 + 16 * (2 * p + 1) + 4 * lg);
      float4 w4v0 = *(const float4*)(sC + 448 + 16 * (2 * p) + 4 * lg);
      float4 w4v1 = *(const float4*)(sC + 448 + 16 * (2 * p + 1) + 4 * lg);
      da += lrelu(aA0[0] + cb0.x) * w4v0.x + lrelu(aA0[1] + cb0.y) * w4v0.y
          + lrelu(aA0[2] + cb0.z) * w4v0.z + lrelu(aA0[3] + cb0.w) * w4v0.w;
      da += lrelu(aA1[0] + cb1.x) * w4v1.x + lrelu(aA1[1] + cb1.y) * w4v1.y
          + lrelu(aA1[2] + cb1.z) * w4v1.z + lrelu(aA1[3] + cb1.w) * w4v1.w;
      db += lrelu(aB0[0] + cb0.x) * w4v0.x + lrelu(aB0[1] + cb0.y) * w4v0.y
          + lrelu(aB0[2] + cb0.z) * w4v0.z + lrelu(aB0[3] + cb0.w) * w4v0.w;
      db += lrelu(aB1[0] + cb1.x) * w4v1.x + lrelu(aB1[1] + cb1.y) * w4v1.y
          + lrelu(aB1[2] + cb1.z) * w4v1.z + lrelu(aB1[3] + cb1.w) * w4v1.w;
    }
    da += __shfl_xor(da, 16, 64); da += __shfl_xor(da, 32, 64);
    db += __shfl_xor(db, 16, 64); db += __shfl_xor(db, 32, 64);
    float eva = expf(da + sC[512]), evb = expf(db + sC[512]);
    if (lg == 0) { eL[r0 + lr] = eva; eL[r0 + 16 + lr] = evb; }
    es += eva + evb;                 // 4x duplicated across lg, scaled at the end
    // ---- convert prefetched rows -> B1a/B1b for next iteration ----
    #pragma unroll
    for (int kt = 0; kt < 4; ++kt) {
      float4 f0 = tA[2 * kt], f1 = tA[2 * kt + 1];
      float4 g0 = tB[2 * kt], g1 = tB[2 * kt + 1];
      bf16x8 a, b;
      a[0] = (__bf16)f0.x; a[1] = (__bf16)f0.y; a[2] = (__bf16)f0.z; a[3] = (__bf16)f0.w;
      a[4] = (__bf16)f1.x; a[5] = (__bf16)f1.y; a[6] = (__bf16)f1.z; a[7] = (__bf16)f1.w;
      b[0] = (__bf16)g0.x; b[1] = (__bf16)g0.y; b[2] = (__bf16)g0.z; b[3] = (__bf16)g0.w;
      b[4] = (__bf16)g1.x; b[5] = (__bf16)g1.y; b[6] = (__bf16)g1.z; b[7] = (__bf16)g1.w;
      B1a[kt] = a; B1b[kt] = b;
    }
  }
  // wave-wide partial softmax denominator (deterministic: one slot per wave)
  #pragma unroll
  for (int off = 1; off < 64; off <<= 1) es += __shfl_xor(es, off, 64);
  if (lane == 0) psum[wid] = 0.25f * es;
}

// ---------------- k_norm: per-block redundant psum reduce + normalize -------------------
__global__ __launch_bounds__(256) void k_norm(const float* __restrict__ eL,
                                              const float* __restrict__ psum,
                                              float* __restrict__ out)
{
  __shared__ float sr[4];
  const int tid = threadIdx.x;
  float s = 0.f;
  #pragma unroll
  for (int k = 0; k < 8; ++k) s += psum[tid + k * 256];
  #pragma unroll
  for (int off = 1; off < 64; off <<= 1) s += __shfl_xor(s, off, 64);
  if ((tid & 63) == 0) sr[tid >> 6] = s;
  __syncthreads();
  const float inv = 1.f / (sr[0] + sr[1] + sr[2] + sr[3]);
  const int i = blockIdx.x * 256 + tid;
  if (i < NN / 4) {
    float4 v = ((const float4*)eL)[i];
    float4 o = {v.x * inv, v.y * inv, v.z * inv, v.w * inv};
    ((float4*)out)[i] = o;
  }
}

extern "C" void kernel_launch(void* const* d_in, const int* in_sizes, int n_in,
                              void* d_out, int out_size, void* d_ws, size_t ws_size,
                              hipStream_t stream) {
  const float* enc = (const float*)d_in[0];
  const int*   cs  = (const int*)d_in[1];
  const float* W1  = (const float*)d_in[2];
  const float* b1  = (const float*)d_in[3];
  const float* W2  = (const float*)d_in[4];
  const float* b2  = (const float*)d_in[5];
  const float* W3  = (const float*)d_in[6];
  const float* b3  = (const float*)d_in[7];
  const float* W4  = (const float*)d_in[8];
  const float* b4  = (const float*)d_in[9];
  float* out = (float*)d_out;

  char* ws = (char*)d_ws;
  float* mu_in  = (float*)(ws + 0);        // 512 B
  float* mu_not = (float*)(ws + 512);      // 512 B
  float* psum   = (float*)(ws + 2048);     // 2048 floats = 8 KB
  float* red2   = (float*)(ws + 16384);    // 64*256*4 = 64 KB
  float* eLbuf  = (float*)(ws + 131072);   // 2 MB (exp(logit) per row)
  // colmax partials alias the eL region: live only BEFORE k_mlp writes eL.
  float* partials = (float*)(ws + 131072); // 2000*256*4 = 2,048,000 B

  k_colmax<<<dim3(NBLK_CM), dim3(256), 0, stream>>>(enc, cs, partials);
  k_red1<<<dim3(64), dim3(256), 0, stream>>>(partials, red2);
  k_red2<<<dim3(1), dim3(1024), 0, stream>>>(red2, mu_in, mu_not);
  k_mlp<<<dim3(256), dim3(512), 0, stream>>>(enc, W1, b1, W2, b2, W3, b3, W4, b4,
                                             mu_in, mu_not, eLbuf, psum);
  k_norm<<<dim3(489), dim3(256), 0, stream>>>(eLbuf, psum, out);
}